// Round 1
// baseline (894.361 us; speedup 1.0000x reference)
//
#include <hip/hip_runtime.h>
#include <cstdint>
#include <cstddef>

// ---------------- problem constants ----------------
constexpr int kN   = 50000;            // nodes
constexpr int kE   = 1600000;          // edges (before self loops)
constexpr int kET  = kE + kN;          // total edges incl self loops
constexpr int kIN  = 128;
constexpr int kHID = 64;
constexpr int kHEADS = 2;
constexpr int kOUT = 16;
constexpr float kNEG = 0.2f;

// ---------------- CSR construction ----------------
__global__ void hist_kernel(const int* __restrict__ ei, int* __restrict__ counts) {
  int i = blockIdx.x * blockDim.x + threadIdx.x;
  if (i >= kET) return;
  int dst = (i < kE) ? ei[kE + i] : (i - kE);
  atomicAdd(&counts[dst], 1);
}

#define SCAN_BLOCK 1024
__global__ __launch_bounds__(SCAN_BLOCK) void scan_local_kernel(
    const int* __restrict__ counts, int* __restrict__ row_ptr,
    int* __restrict__ block_sums, int n) {
  __shared__ int s[SCAN_BLOCK];
  const int t = threadIdx.x;
  const int i = blockIdx.x * SCAN_BLOCK + t;
  int v = (i < n) ? counts[i] : 0;
  s[t] = v;
  __syncthreads();
  for (int off = 1; off < SCAN_BLOCK; off <<= 1) {
    int x = (t >= off) ? s[t - off] : 0;
    __syncthreads();
    s[t] += x;
    __syncthreads();
  }
  if (i < n) row_ptr[i + 1] = s[t];
  if (t == SCAN_BLOCK - 1) block_sums[blockIdx.x] = s[t];
  if (i == 0) row_ptr[0] = 0;
}

__global__ void scan_carry_kernel(int* block_sums, int nb) {
  if (threadIdx.x == 0 && blockIdx.x == 0) {
    int run = 0;
    for (int b = 0; b < nb; b++) { int tmp = block_sums[b]; block_sums[b] = run; run += tmp; }
  }
}

__global__ __launch_bounds__(SCAN_BLOCK) void scan_add_kernel(
    int* __restrict__ row_ptr, int* __restrict__ cursor,
    const int* __restrict__ block_sums, int n) {
  const int i = blockIdx.x * SCAN_BLOCK + threadIdx.x;
  if (i < n) {
    const int cnt = cursor[i];
    const int incl = row_ptr[i + 1] + block_sums[blockIdx.x];
    row_ptr[i + 1] = incl;
    cursor[i] = incl - cnt;   // exclusive offset -> scatter cursor
  }
}

__global__ void scatter_kernel(const int* __restrict__ ei, int* __restrict__ cursor,
                               int* __restrict__ col_src) {
  int i = blockIdx.x * blockDim.x + threadIdx.x;
  if (i >= kET) return;
  int src, dst;
  if (i < kE) { src = ei[i]; dst = ei[kE + i]; }
  else        { src = i - kE; dst = src; }
  int pos = atomicAdd(&cursor[dst], 1);
  col_src[pos] = src;
}

// ---------------- dense transform: H = X @ W  (X:[n,128], W:[128,MOUT]) ----------------
template<int MOUT, int ROWS>
__global__ __launch_bounds__(256) void transform_kernel(
    const float* __restrict__ X, const float* __restrict__ W,
    float* __restrict__ H, int n) {
  constexpr int G = 256 / MOUT;      // row groups
  constexpr int RPT = ROWS / G;      // rows per thread
  __shared__ float Xs[ROWS][129];
  const int t = threadIdx.x;
  const int row0 = blockIdx.x * ROWS;
  for (int i = t; i < ROWS * 32; i += 256) {
    const int r = i >> 5, kc = i & 31;
    float4 v = make_float4(0.f, 0.f, 0.f, 0.f);
    if (row0 + r < n) v = ((const float4*)(X + (size_t)(row0 + r) * 128))[kc];
    Xs[r][kc * 4 + 0] = v.x; Xs[r][kc * 4 + 1] = v.y;
    Xs[r][kc * 4 + 2] = v.z; Xs[r][kc * 4 + 3] = v.w;
  }
  __syncthreads();
  const int col = t % MOUT;
  const int rg = t / MOUT;
  float acc[RPT];
#pragma unroll
  for (int j = 0; j < RPT; j++) acc[j] = 0.f;
#pragma unroll 4
  for (int k = 0; k < 128; k++) {
    const float w = W[k * MOUT + col];
#pragma unroll
    for (int j = 0; j < RPT; j++) acc[j] += Xs[rg + j * G][k] * w;
  }
#pragma unroll
  for (int j = 0; j < RPT; j++) {
    const int r = row0 + rg + j * G;
    if (r < n) H[(size_t)r * MOUT + col] = acc[j];
  }
}

// ---------------- per-node attention coefficients ----------------
// C=64: H row = 128 floats, one wave per node
__global__ void alpha64_kernel(const float* __restrict__ H, const float* __restrict__ as,
                               const float* __restrict__ ad, float2* __restrict__ AS,
                               float2* __restrict__ AD, int n) {
  const int wid = threadIdx.x >> 6, lane = threadIdx.x & 63;
  const int node = blockIdx.x * (blockDim.x >> 6) + wid;
  if (node >= n) return;
  const float* hrow = H + (size_t)node * 128;
  const float h0 = hrow[lane], h1 = hrow[64 + lane];
  float s0 = h0 * as[lane], s1 = h1 * as[64 + lane];
  float d0 = h0 * ad[lane], d1 = h1 * ad[64 + lane];
#pragma unroll
  for (int off = 32; off >= 1; off >>= 1) {
    s0 += __shfl_xor(s0, off); s1 += __shfl_xor(s1, off);
    d0 += __shfl_xor(d0, off); d1 += __shfl_xor(d1, off);
  }
  if (lane == 0) { AS[node] = make_float2(s0, s1); AD[node] = make_float2(d0, d1); }
}

// C=16: H row = 32 floats; (2,16) flat layout => index = lane for lane<32
__global__ void alpha16_kernel(const float* __restrict__ H, const float* __restrict__ as,
                               const float* __restrict__ ad, float2* __restrict__ AS,
                               float2* __restrict__ AD, int n) {
  const int wid = threadIdx.x >> 6, lane = threadIdx.x & 63;
  const int node = blockIdx.x * (blockDim.x >> 6) + wid;
  if (node >= n) return;
  float sv = 0.f, dv = 0.f;
  if (lane < 32) {
    const float h = H[(size_t)node * 32 + lane];
    sv = h * as[lane];
    dv = h * ad[lane];
  }
#pragma unroll
  for (int off = 8; off >= 1; off >>= 1) { sv += __shfl_xor(sv, off); dv += __shfl_xor(dv, off); }
  const float s1 = __shfl(sv, 16);
  const float d1 = __shfl(dv, 16);
  if (lane == 0) { AS[node] = make_float2(sv, s1); AD[node] = make_float2(dv, d1); }
}

// ---------------- fused softmax + aggregate ----------------
// MODE 0: OUT[n, 2C] = elu(agg + bias)      (layers 0,1)
// MODE 1: OUT[n, C]  = mean_heads(agg) + b  (layer 2)
template<int C, int MODE>
__global__ __launch_bounds__(2 * C) void agg_kernel(
    const float* __restrict__ H, const float2* __restrict__ AS,
    const float2* __restrict__ AD, const int* __restrict__ row_ptr,
    const int* __restrict__ col_src, const float* __restrict__ bias,
    float* __restrict__ OUT) {
  constexpr int T = 2 * C;
  constexpr int CAP = 1024;
  __shared__ float s_alpha[CAP * 2];
  __shared__ int s_src[CAP];
  __shared__ float s_red[4]; // m0,m1,l0,l1
  const int node = blockIdx.x;
  const int t = threadIdx.x;
  const int hh = t / C;
  const int cc = t % C;
  const int begin = row_ptr[node];
  const int d = row_ptr[node + 1] - begin;
  const float2 adn2 = AD[node];
  const float ad_n = (hh == 0) ? adn2.x : adn2.y;

  // pass 1: segment max (and cache src ids)
  float lm = -3.0e38f;
  for (int j = cc; j < d; j += C) {
    const int src = col_src[begin + j];
    if (hh == 0 && j < CAP) s_src[j] = src;
    const float2 a = AS[src];
    float e = ((hh == 0) ? a.x : a.y) + ad_n;
    e = (e > 0.f) ? e : kNEG * e;
    lm = fmaxf(lm, e);
  }
#pragma unroll
  for (int off = C / 2; off >= 1; off >>= 1) lm = fmaxf(lm, __shfl_xor(lm, off));
  if (cc == 0) s_red[hh] = lm;
  __syncthreads();
  const float m = s_red[hh];

  // pass 2: sum of exp (cache weights)
  float ls = 0.f;
  for (int j = cc; j < d; j += C) {
    const int src = (j < CAP) ? s_src[j] : col_src[begin + j];
    const float2 a = AS[src];
    float e = ((hh == 0) ? a.x : a.y) + ad_n;
    e = (e > 0.f) ? e : kNEG * e;
    const float w = __expf(e - m);
    if (j < CAP) s_alpha[j * 2 + hh] = w;
    ls += w;
  }
#pragma unroll
  for (int off = C / 2; off >= 1; off >>= 1) ls += __shfl_xor(ls, off);
  if (cc == 0) s_red[2 + hh] = ls;
  __syncthreads();
  const float inv = 1.0f / (s_red[2 + hh] + 1e-16f);

  // pass 3: weighted gather-accumulate
  float acc = 0.f;
#pragma unroll 2
  for (int j = 0; j < d; j++) {
    int src; float w;
    if (j < CAP) { src = s_src[j]; w = s_alpha[j * 2 + hh]; }
    else {
      src = col_src[begin + j];
      const float2 a = AS[src];
      float e = ((hh == 0) ? a.x : a.y) + ad_n;
      e = (e > 0.f) ? e : kNEG * e;
      w = __expf(e - m);
    }
    acc = fmaf(w * inv, H[(size_t)src * T + t], acc);
  }

  if constexpr (MODE == 0) {
    float v = acc + bias[t];
    v = (v > 0.f) ? v : expm1f(v);
    OUT[(size_t)node * T + t] = v;
  } else {
    const float other = __shfl_down(acc, C);
    if (t < C) OUT[(size_t)node * C + t] = 0.5f * (acc + other) + bias[t];
  }
}

// ---------------- host launcher ----------------
extern "C" void kernel_launch(void* const* d_in, const int* in_sizes, int n_in,
                              void* d_out, int out_size, void* d_ws, size_t ws_size,
                              hipStream_t stream) {
  const float* x   = (const float*)d_in[0];
  const int*   ei  = (const int*)d_in[1];
  const float* W0  = (const float*)d_in[2];
  const float* as0 = (const float*)d_in[3];
  const float* ad0 = (const float*)d_in[4];
  const float* b0  = (const float*)d_in[5];
  const float* W1  = (const float*)d_in[6];
  const float* as1 = (const float*)d_in[7];
  const float* ad1 = (const float*)d_in[8];
  const float* b1  = (const float*)d_in[9];
  const float* W2  = (const float*)d_in[10];
  const float* as2 = (const float*)d_in[11];
  const float* ad2 = (const float*)d_in[12];
  const float* b2  = (const float*)d_in[13];
  float* out = (float*)d_out;

  // workspace layout
  size_t off = 0;
  auto alloc = [&](size_t bytes) -> void* {
    void* p = (char*)d_ws + off;
    off += (bytes + 255) & ~(size_t)255;
    return p;
  };
  int*    row_ptr = (int*)alloc(sizeof(int) * (kN + 1));
  int*    cursor  = (int*)alloc(sizeof(int) * kN);
  int*    col_src = (int*)alloc(sizeof(int) * kET);
  int*    bsums   = (int*)alloc(sizeof(int) * 64);
  float2* AS      = (float2*)alloc(sizeof(float2) * kN);
  float2* AD      = (float2*)alloc(sizeof(float2) * kN);
  float*  bufA    = (float*)alloc(sizeof(float) * (size_t)kN * 128);
  float*  bufB    = (float*)alloc(sizeof(float) * (size_t)kN * 128);
  (void)ws_size; (void)in_sizes; (void)n_in; (void)out_size;

  // ---- CSR build (edge list identical for all layers) ----
  hipMemsetAsync(cursor, 0, sizeof(int) * kN, stream);
  const int egrid = (kET + 255) / 256;
  hist_kernel<<<egrid, 256, 0, stream>>>(ei, cursor);
  const int NB = (kN + SCAN_BLOCK - 1) / SCAN_BLOCK;
  scan_local_kernel<<<NB, SCAN_BLOCK, 0, stream>>>(cursor, row_ptr, bsums, kN);
  scan_carry_kernel<<<1, 1, 0, stream>>>(bsums, NB);
  scan_add_kernel<<<NB, SCAN_BLOCK, 0, stream>>>(row_ptr, cursor, bsums, kN);
  scatter_kernel<<<egrid, 256, 0, stream>>>(ei, cursor, col_src);

  // ---- layer 0 ----
  transform_kernel<128, 16><<<(kN + 15) / 16, 256, 0, stream>>>(x, W0, bufA, kN);
  alpha64_kernel<<<(kN + 3) / 4, 256, 0, stream>>>(bufA, as0, ad0, AS, AD, kN);
  agg_kernel<64, 0><<<kN, 128, 0, stream>>>(bufA, AS, AD, row_ptr, col_src, b0, bufB);

  // ---- layer 1 ----
  transform_kernel<128, 16><<<(kN + 15) / 16, 256, 0, stream>>>(bufB, W1, bufA, kN);
  alpha64_kernel<<<(kN + 3) / 4, 256, 0, stream>>>(bufA, as1, ad1, AS, AD, kN);
  agg_kernel<64, 0><<<kN, 128, 0, stream>>>(bufA, AS, AD, row_ptr, col_src, b1, bufB);

  // ---- layer 2 ----
  transform_kernel<32, 32><<<(kN + 31) / 32, 256, 0, stream>>>(bufB, W2, bufA, kN);
  alpha16_kernel<<<(kN + 3) / 4, 256, 0, stream>>>(bufA, as2, ad2, AS, AD, kN);
  agg_kernel<16, 1><<<kN, 32, 0, stream>>>(bufA, AS, AD, row_ptr, col_src, b2, out);
}

// Round 2
// 612.475 us; speedup vs baseline: 1.4602x; 1.4602x over previous
//
#include <hip/hip_runtime.h>
#include <cstdint>
#include <cstddef>

// ---------------- problem constants ----------------
constexpr int kN   = 50000;            // nodes
constexpr int kE   = 1600000;          // edges (before self loops)
constexpr int kET  = kE + kN;          // total edges incl self loops
constexpr float kNEG = 0.2f;

// ---------------- CSR construction ----------------
__global__ void hist_kernel(const int* __restrict__ ei, int* __restrict__ counts) {
  int i = blockIdx.x * blockDim.x + threadIdx.x;
  if (i >= kET) return;
  int dst = (i < kE) ? ei[kE + i] : (i - kE);
  atomicAdd(&counts[dst], 1);
}

#define SCAN_BLOCK 1024
__global__ __launch_bounds__(SCAN_BLOCK) void scan_local_kernel(
    const int* __restrict__ counts, int* __restrict__ row_ptr,
    int* __restrict__ block_sums, int n) {
  __shared__ int s[SCAN_BLOCK];
  const int t = threadIdx.x;
  const int i = blockIdx.x * SCAN_BLOCK + t;
  int v = (i < n) ? counts[i] : 0;
  s[t] = v;
  __syncthreads();
  for (int off = 1; off < SCAN_BLOCK; off <<= 1) {
    int x = (t >= off) ? s[t - off] : 0;
    __syncthreads();
    s[t] += x;
    __syncthreads();
  }
  if (i < n) row_ptr[i + 1] = s[t];
  if (t == SCAN_BLOCK - 1) block_sums[blockIdx.x] = s[t];
  if (i == 0) row_ptr[0] = 0;
}

__global__ void scan_carry_kernel(int* block_sums, int nb) {
  if (threadIdx.x == 0 && blockIdx.x == 0) {
    int run = 0;
    for (int b = 0; b < nb; b++) { int tmp = block_sums[b]; block_sums[b] = run; run += tmp; }
  }
}

__global__ __launch_bounds__(SCAN_BLOCK) void scan_add_kernel(
    int* __restrict__ row_ptr, int* __restrict__ cursor,
    const int* __restrict__ block_sums, int n) {
  const int i = blockIdx.x * SCAN_BLOCK + threadIdx.x;
  if (i < n) {
    const int cnt = cursor[i];
    const int incl = row_ptr[i + 1] + block_sums[blockIdx.x];
    row_ptr[i + 1] = incl;
    cursor[i] = incl - cnt;   // exclusive offset -> scatter cursor
  }
}

__global__ void scatter_kernel(const int* __restrict__ ei, int* __restrict__ cursor,
                               int* __restrict__ col_src) {
  int i = blockIdx.x * blockDim.x + threadIdx.x;
  if (i >= kET) return;
  int src, dst;
  if (i < kE) { src = ei[i]; dst = ei[kE + i]; }
  else        { src = i - kE; dst = src; }
  int pos = atomicAdd(&cursor[dst], 1);
  col_src[pos] = src;
}

// ---------------- dense transform: H = X @ W (X:[n,128], W:[128,MOUT]) ----------------
// register-tiled: thread computes TR rows x 4 cols; W rows read as float4 (L1-resident)
template<int MOUT, int TR>
__global__ __launch_bounds__(256) void transform2_kernel(
    const float* __restrict__ X, const float* __restrict__ W,
    float* __restrict__ H, int n) {
  constexpr int CG = MOUT / 4;       // col groups of 4
  constexpr int RG = 256 / CG;       // row groups
  constexpr int ROWS = RG * TR;      // rows per block
  __shared__ float Xs[ROWS][132];    // 132: keep 16B alignment per row
  const int t = threadIdx.x;
  const int row0 = blockIdx.x * ROWS;
  for (int i = t; i < ROWS * 32; i += 256) {
    const int r = i >> 5, kc = i & 31;
    float4 v = make_float4(0.f, 0.f, 0.f, 0.f);
    if (row0 + r < n) v = ((const float4*)(X + (size_t)(row0 + r) * 128))[kc];
    *(float4*)(&Xs[r][kc * 4]) = v;
  }
  __syncthreads();
  const int cg = t % CG;
  const int rg = t / CG;
  const int c0 = cg * 4;
  float4 acc[TR];
#pragma unroll
  for (int i = 0; i < TR; i++) acc[i] = make_float4(0.f, 0.f, 0.f, 0.f);
  for (int k4 = 0; k4 < 32; k4++) {
    float4 wv0 = *(const float4*)(W + (size_t)(k4 * 4 + 0) * MOUT + c0);
    float4 wv1 = *(const float4*)(W + (size_t)(k4 * 4 + 1) * MOUT + c0);
    float4 wv2 = *(const float4*)(W + (size_t)(k4 * 4 + 2) * MOUT + c0);
    float4 wv3 = *(const float4*)(W + (size_t)(k4 * 4 + 3) * MOUT + c0);
#pragma unroll
    for (int i = 0; i < TR; i++) {
      const float4 xv = *(const float4*)(&Xs[rg * TR + i][k4 * 4]);
      acc[i].x = fmaf(xv.x, wv0.x, acc[i].x); acc[i].y = fmaf(xv.x, wv0.y, acc[i].y);
      acc[i].z = fmaf(xv.x, wv0.z, acc[i].z); acc[i].w = fmaf(xv.x, wv0.w, acc[i].w);
      acc[i].x = fmaf(xv.y, wv1.x, acc[i].x); acc[i].y = fmaf(xv.y, wv1.y, acc[i].y);
      acc[i].z = fmaf(xv.y, wv1.z, acc[i].z); acc[i].w = fmaf(xv.y, wv1.w, acc[i].w);
      acc[i].x = fmaf(xv.z, wv2.x, acc[i].x); acc[i].y = fmaf(xv.z, wv2.y, acc[i].y);
      acc[i].z = fmaf(xv.z, wv2.z, acc[i].z); acc[i].w = fmaf(xv.z, wv2.w, acc[i].w);
      acc[i].x = fmaf(xv.w, wv3.x, acc[i].x); acc[i].y = fmaf(xv.w, wv3.y, acc[i].y);
      acc[i].z = fmaf(xv.w, wv3.z, acc[i].z); acc[i].w = fmaf(xv.w, wv3.w, acc[i].w);
    }
  }
#pragma unroll
  for (int i = 0; i < TR; i++) {
    const int r = row0 + rg * TR + i;
    if (r < n) *(float4*)(H + (size_t)r * MOUT + c0) = acc[i];
  }
}

// ---------------- per-node attention coefficients ----------------
__global__ void alpha64_kernel(const float* __restrict__ H, const float* __restrict__ as,
                               const float* __restrict__ ad, float2* __restrict__ AS,
                               float2* __restrict__ AD, int n) {
  const int wid = threadIdx.x >> 6, lane = threadIdx.x & 63;
  const int node = blockIdx.x * (blockDim.x >> 6) + wid;
  if (node >= n) return;
  const float* hrow = H + (size_t)node * 128;
  const float h0 = hrow[lane], h1 = hrow[64 + lane];
  float s0 = h0 * as[lane], s1 = h1 * as[64 + lane];
  float d0 = h0 * ad[lane], d1 = h1 * ad[64 + lane];
#pragma unroll
  for (int off = 32; off >= 1; off >>= 1) {
    s0 += __shfl_xor(s0, off); s1 += __shfl_xor(s1, off);
    d0 += __shfl_xor(d0, off); d1 += __shfl_xor(d1, off);
  }
  if (lane == 0) { AS[node] = make_float2(s0, s1); AD[node] = make_float2(d0, d1); }
}

__global__ void alpha16_kernel(const float* __restrict__ H, const float* __restrict__ as,
                               const float* __restrict__ ad, float2* __restrict__ AS,
                               float2* __restrict__ AD, int n) {
  const int wid = threadIdx.x >> 6, lane = threadIdx.x & 63;
  const int node = blockIdx.x * (blockDim.x >> 6) + wid;
  if (node >= n) return;
  float sv = 0.f, dv = 0.f;
  if (lane < 32) {
    const float h = H[(size_t)node * 32 + lane];
    sv = h * as[lane];
    dv = h * ad[lane];
  }
#pragma unroll
  for (int off = 8; off >= 1; off >>= 1) { sv += __shfl_xor(sv, off); dv += __shfl_xor(dv, off); }
  const float s1 = __shfl(sv, 16);
  const float d1 = __shfl(dv, 16);
  if (lane == 0) { AS[node] = make_float2(sv, s1); AD[node] = make_float2(dv, d1); }
}

// ---------------- fused softmax + aggregate (wave-per-node) ----------------
// No max subtraction: e = leaky(as+ad) is O(5) for this data; exp(e)/sum(exp(e))
// is mathematically identical to the max-shifted form and safe in fp32 here.
// MODE 0: OUT[n,128] = elu(agg + bias)    (C=64, layers 0,1)
// MODE 1: OUT[n,16]  = mean_heads(agg)+b  (C=16, layer 2)
template<int C, int MODE>
__global__ __launch_bounds__(256) void agg_kernel(
    const float* __restrict__ H, const float2* __restrict__ AS,
    const float2* __restrict__ AD, const int* __restrict__ row_ptr,
    const int* __restrict__ col_src, const float* __restrict__ bias,
    float* __restrict__ OUT) {
  constexpr int CAP = 128;           // cached edges per node (fallback beyond)
  __shared__ int    s_src[4 * CAP];
  __shared__ float2 s_w[4 * CAP];
  const int wid  = threadIdx.x >> 6;
  const int lane = threadIdx.x & 63;
  const int node = blockIdx.x * 4 + wid;
  const int base = wid * CAP;

  const int begin = row_ptr[node];
  const int d = row_ptr[node + 1] - begin;
  const float2 adn = AD[node];

  // ---- pass A: edge-parallel weights (lanes stride edges) ----
  float sum0 = 0.f, sum1 = 0.f;
  for (int j = lane; j < d; j += 64) {
    const int src = col_src[begin + j];
    const float2 a = AS[src];
    float e0 = a.x + adn.x; e0 = (e0 > 0.f) ? e0 : kNEG * e0;
    float e1 = a.y + adn.y; e1 = (e1 > 0.f) ? e1 : kNEG * e1;
    const float w0 = __expf(e0), w1 = __expf(e1);
    if (j < CAP) { s_src[base + j] = src; s_w[base + j] = make_float2(w0, w1); }
    sum0 += w0; sum1 += w1;
  }
#pragma unroll
  for (int off = 32; off >= 1; off >>= 1) {
    sum0 += __shfl_xor(sum0, off);
    sum1 += __shfl_xor(sum1, off);
  }
  const float inv0 = 1.0f / (sum0 + 1e-16f);
  const float inv1 = 1.0f / (sum1 + 1e-16f);
  __syncthreads();   // make per-wave LDS region visible across lanes

  const int dcap = (d < CAP) ? d : CAP;

  if constexpr (MODE == 0) {
    // ---- pass B: channel-parallel gather; lane covers channels (2l,2l+1) ----
    const float inv = (lane < 32) ? inv0 : inv1;
    float accx = 0.f, accy = 0.f;
#pragma unroll 4
    for (int j = 0; j < dcap; j++) {
      const int src = s_src[base + j];
      const float2 wv = s_w[base + j];
      const float w = (lane < 32) ? wv.x : wv.y;
      const float2 v = *(const float2*)(H + (size_t)src * 128 + 2 * lane);
      accx = fmaf(w, v.x, accx);
      accy = fmaf(w, v.y, accy);
    }
    for (int j = CAP; j < d; j++) {       // rare fallback: recompute weight
      const int src = col_src[begin + j];
      const float2 a = AS[src];
      float e0 = a.x + adn.x; e0 = (e0 > 0.f) ? e0 : kNEG * e0;
      float e1 = a.y + adn.y; e1 = (e1 > 0.f) ? e1 : kNEG * e1;
      const float w = (lane < 32) ? __expf(e0) : __expf(e1);
      const float2 v = *(const float2*)(H + (size_t)src * 128 + 2 * lane);
      accx = fmaf(w, v.x, accx);
      accy = fmaf(w, v.y, accy);
    }
    accx *= inv; accy *= inv;
    const int ch = 2 * lane;
    float vx = accx + bias[ch];
    float vy = accy + bias[ch + 1];
    vx = (vx > 0.f) ? vx : expm1f(vx);
    vy = (vy > 0.f) ? vy : expm1f(vy);
    *(float2*)(OUT + (size_t)node * 128 + ch) = make_float2(vx, vy);
  } else {
    // ---- C=16: lanes 0-31 edge j, lanes 32-63 edge j+1; channel = lane&31 ----
    const int ch = lane & 31;
    const int hsel = (ch >= 16);
    const int esel = lane >> 5;
    const float inv = hsel ? inv1 : inv0;
    float acc = 0.f;
    int j = 0;
    for (; j + 1 < dcap; j += 2) {
      const int jj = j + esel;
      const int src = s_src[base + jj];
      const float2 wv = s_w[base + jj];
      const float w = hsel ? wv.y : wv.x;
      acc = fmaf(w, H[(size_t)src * 32 + ch], acc);
    }
    if (j < dcap && esel == 0) {          // odd leftover
      const int src = s_src[base + j];
      const float2 wv = s_w[base + j];
      const float w = hsel ? wv.y : wv.x;
      acc = fmaf(w, H[(size_t)src * 32 + ch], acc);
    }
    if (esel == 0) {
      for (int jt = CAP; jt < d; jt++) {  // rare fallback
        const int src = col_src[begin + jt];
        const float2 a = AS[src];
        float e0 = a.x + adn.x; e0 = (e0 > 0.f) ? e0 : kNEG * e0;
        float e1 = a.y + adn.y; e1 = (e1 > 0.f) ? e1 : kNEG * e1;
        const float w = hsel ? __expf(e1) : __expf(e0);
        acc = fmaf(w, H[(size_t)src * 32 + ch], acc);
      }
    }
    acc *= inv;
    acc += __shfl_down(acc, 32);          // combine the two edge-halves
    const float other = __shfl(acc, lane + 16);
    if (lane < 16) OUT[(size_t)node * 16 + lane] = 0.5f * (acc + other) + bias[lane];
  }
}

// ---------------- host launcher ----------------
extern "C" void kernel_launch(void* const* d_in, const int* in_sizes, int n_in,
                              void* d_out, int out_size, void* d_ws, size_t ws_size,
                              hipStream_t stream) {
  const float* x   = (const float*)d_in[0];
  const int*   ei  = (const int*)d_in[1];
  const float* W0  = (const float*)d_in[2];
  const float* as0 = (const float*)d_in[3];
  const float* ad0 = (const float*)d_in[4];
  const float* b0  = (const float*)d_in[5];
  const float* W1  = (const float*)d_in[6];
  const float* as1 = (const float*)d_in[7];
  const float* ad1 = (const float*)d_in[8];
  const float* b1  = (const float*)d_in[9];
  const float* W2  = (const float*)d_in[10];
  const float* as2 = (const float*)d_in[11];
  const float* ad2 = (const float*)d_in[12];
  const float* b2  = (const float*)d_in[13];
  float* out = (float*)d_out;

  size_t off = 0;
  auto alloc = [&](size_t bytes) -> void* {
    void* p = (char*)d_ws + off;
    off += (bytes + 255) & ~(size_t)255;
    return p;
  };
  int*    row_ptr = (int*)alloc(sizeof(int) * (kN + 1));
  int*    cursor  = (int*)alloc(sizeof(int) * kN);
  int*    col_src = (int*)alloc(sizeof(int) * kET);
  int*    bsums   = (int*)alloc(sizeof(int) * 64);
  float2* AS      = (float2*)alloc(sizeof(float2) * kN);
  float2* AD      = (float2*)alloc(sizeof(float2) * kN);
  float*  bufA    = (float*)alloc(sizeof(float) * (size_t)kN * 128);
  float*  bufB    = (float*)alloc(sizeof(float) * (size_t)kN * 128);
  (void)ws_size; (void)in_sizes; (void)n_in; (void)out_size;

  // ---- CSR build (edge list identical for all layers) ----
  hipMemsetAsync(cursor, 0, sizeof(int) * kN, stream);
  const int egrid = (kET + 255) / 256;
  hist_kernel<<<egrid, 256, 0, stream>>>(ei, cursor);
  const int NB = (kN + SCAN_BLOCK - 1) / SCAN_BLOCK;
  scan_local_kernel<<<NB, SCAN_BLOCK, 0, stream>>>(cursor, row_ptr, bsums, kN);
  scan_carry_kernel<<<1, 1, 0, stream>>>(bsums, NB);
  scan_add_kernel<<<NB, SCAN_BLOCK, 0, stream>>>(row_ptr, cursor, bsums, kN);
  scatter_kernel<<<egrid, 256, 0, stream>>>(ei, cursor, col_src);

  // ---- layer 0 ----
  transform2_kernel<128, 4><<<(kN + 31) / 32, 256, 0, stream>>>(x, W0, bufA, kN);
  alpha64_kernel<<<(kN + 3) / 4, 256, 0, stream>>>(bufA, as0, ad0, AS, AD, kN);
  agg_kernel<64, 0><<<(kN + 3) / 4, 256, 0, stream>>>(bufA, AS, AD, row_ptr, col_src, b0, bufB);

  // ---- layer 1 ----
  transform2_kernel<128, 4><<<(kN + 31) / 32, 256, 0, stream>>>(bufB, W1, bufA, kN);
  alpha64_kernel<<<(kN + 3) / 4, 256, 0, stream>>>(bufA, as1, ad1, AS, AD, kN);
  agg_kernel<64, 0><<<(kN + 3) / 4, 256, 0, stream>>>(bufA, AS, AD, row_ptr, col_src, b1, bufB);

  // ---- layer 2 ----
  transform2_kernel<32, 1><<<(kN + 31) / 32, 256, 0, stream>>>(bufB, W2, bufA, kN);
  alpha16_kernel<<<(kN + 3) / 4, 256, 0, stream>>>(bufA, as2, ad2, AS, AD, kN);
  agg_kernel<16, 1><<<(kN + 3) / 4, 256, 0, stream>>>(bufA, AS, AD, row_ptr, col_src, b2, out);
}

// Round 3
// 476.021 us; speedup vs baseline: 1.8788x; 1.2867x over previous
//
#include <hip/hip_runtime.h>
#include <cstdint>
#include <cstddef>

// ---------------- problem constants ----------------
constexpr int kN   = 50000;            // nodes
constexpr int kE   = 1600000;          // edges (before self loops)
constexpr int kET  = kE + kN;          // total edges incl self loops
constexpr float kNEG = 0.2f;
constexpr int NBUCK = (kN + 127) / 128;        // 391 buckets of 128 dst nodes
constexpr int PCHUNK = 8192;                   // edges per partition block
constexpr int PGRID = (kET + PCHUNK - 1) / PCHUNK;

// ---------------- CSR build: bucketed counting sort ----------------
// Pass 1: bucket-level histogram (LDS-staged; few global atomics)
__global__ __launch_bounds__(256) void bucket_hist_kernel(const int* __restrict__ ei,
                                                          int* __restrict__ gcnt) {
  __shared__ int h[NBUCK];
  const int t = threadIdx.x;
  for (int i = t; i < NBUCK; i += 256) h[i] = 0;
  __syncthreads();
  const int c0 = blockIdx.x * PCHUNK;
  const int cend = (c0 + PCHUNK < kET) ? c0 + PCHUNK : kET;
  for (int i = c0 + t; i < cend; i += 256) {
    const int dst = (i < kE) ? ei[kE + i] : (i - kE);
    atomicAdd(&h[dst >> 7], 1);
  }
  __syncthreads();
  for (int i = t; i < NBUCK; i += 256) if (h[i]) atomicAdd(&gcnt[i], h[i]);
}

// Pass 2: exclusive scan of bucket counts -> bucket base + partition cursor
__global__ __launch_bounds__(512) void bucket_scan_kernel(const int* __restrict__ gcnt,
                                                          int* __restrict__ base,
                                                          int* __restrict__ cursor) {
  __shared__ int s[512];
  const int t = threadIdx.x;
  const int myc = (t < NBUCK) ? gcnt[t] : 0;
  s[t] = myc;
  __syncthreads();
  for (int off = 1; off < 512; off <<= 1) {
    const int v = (t >= off) ? s[t - off] : 0;
    __syncthreads();
    s[t] += v;
    __syncthreads();
  }
  if (t < NBUCK) {
    const int excl = s[t] - myc;
    base[t] = excl;
    cursor[t] = excl;
  }
  if (t == 0) base[NBUCK] = kET;
}

// Pass 3: partition edges into bucket regions of `part`
// entry = (dst&127)<<16 | src   (src < 50000 < 2^16)
__global__ __launch_bounds__(256) void partition_kernel(const int* __restrict__ ei,
                                                        int* __restrict__ cursor,
                                                        unsigned* __restrict__ part) {
  __shared__ int hist[NBUCK];
  __shared__ int resv[NBUCK];
  __shared__ int lcnt[NBUCK];
  const int t = threadIdx.x;
  for (int i = t; i < NBUCK; i += 256) hist[i] = 0;
  __syncthreads();
  const int c0 = blockIdx.x * PCHUNK;
  const int cend = (c0 + PCHUNK < kET) ? c0 + PCHUNK : kET;
  for (int i = c0 + t; i < cend; i += 256) {
    const int dst = (i < kE) ? ei[kE + i] : (i - kE);
    atomicAdd(&hist[dst >> 7], 1);
  }
  __syncthreads();
  for (int i = t; i < NBUCK; i += 256) {
    lcnt[i] = 0;
    if (hist[i]) resv[i] = atomicAdd(&cursor[i], hist[i]);
  }
  __syncthreads();
  for (int i = c0 + t; i < cend; i += 256) {
    int src, dst;
    if (i < kE) { src = ei[i]; dst = ei[kE + i]; }
    else        { src = i - kE; dst = src; }
    const int b = dst >> 7;
    const int off = atomicAdd(&lcnt[b], 1);
    part[resv[b] + off] = ((unsigned)(dst & 127) << 16) | (unsigned)src;
  }
}

// Pass 4: per-bucket node histogram + scan -> row_ptr; scatter col_src (L2-local)
__global__ __launch_bounds__(256) void finalize_kernel(const unsigned* __restrict__ part,
                                                       const int* __restrict__ base,
                                                       int* __restrict__ row_ptr,
                                                       int* __restrict__ col_src) {
  __shared__ int cnt[128];
  __shared__ int sc[128];
  __shared__ int nbase[128];
  const int b = blockIdx.x, t = threadIdx.x;
  const int lo = base[b], hi = base[b + 1];
  if (t < 128) cnt[t] = 0;
  __syncthreads();
  for (int j = lo + t; j < hi; j += 256) atomicAdd(&cnt[part[j] >> 16], 1);
  __syncthreads();
  if (t < 128) sc[t] = cnt[t];
  __syncthreads();
  for (int off = 1; off < 128; off <<= 1) {
    int v = 0;
    if (t < 128 && t >= off) v = sc[t - off];
    __syncthreads();
    if (t < 128) sc[t] += v;
    __syncthreads();
  }
  if (t < 128) {
    nbase[t] = lo + sc[t] - cnt[t];
    const int node = b * 128 + t;
    if (node < kN) row_ptr[node] = nbase[t];
    cnt[t] = 0;
  }
  if (b == 0 && t == 255) row_ptr[kN] = kET;
  __syncthreads();
  for (int j = lo + t; j < hi; j += 256) {
    const unsigned v = part[j];
    const int nl = v >> 16;
    const int pos = nbase[nl] + atomicAdd(&cnt[nl], 1);
    col_src[pos] = (int)(v & 0xffffu);
  }
}

// ---------------- dense transform: H = X @ W (X:[n,128], W:[128,MOUT]) ----------------
template<int MOUT, int TR>
__global__ __launch_bounds__(256) void transform2_kernel(
    const float* __restrict__ X, const float* __restrict__ W,
    float* __restrict__ H, int n) {
  constexpr int CG = MOUT / 4;       // col groups of 4
  constexpr int RG = 256 / CG;       // row groups
  constexpr int ROWS = RG * TR;      // rows per block
  __shared__ float Xs[ROWS][132];
  const int t = threadIdx.x;
  const int row0 = blockIdx.x * ROWS;
  for (int i = t; i < ROWS * 32; i += 256) {
    const int r = i >> 5, kc = i & 31;
    float4 v = make_float4(0.f, 0.f, 0.f, 0.f);
    if (row0 + r < n) v = ((const float4*)(X + (size_t)(row0 + r) * 128))[kc];
    *(float4*)(&Xs[r][kc * 4]) = v;
  }
  __syncthreads();
  const int cg = t % CG;
  const int rg = t / CG;
  const int c0 = cg * 4;
  float4 acc[TR];
#pragma unroll
  for (int i = 0; i < TR; i++) acc[i] = make_float4(0.f, 0.f, 0.f, 0.f);
  for (int k4 = 0; k4 < 32; k4++) {
    float4 wv0 = *(const float4*)(W + (size_t)(k4 * 4 + 0) * MOUT + c0);
    float4 wv1 = *(const float4*)(W + (size_t)(k4 * 4 + 1) * MOUT + c0);
    float4 wv2 = *(const float4*)(W + (size_t)(k4 * 4 + 2) * MOUT + c0);
    float4 wv3 = *(const float4*)(W + (size_t)(k4 * 4 + 3) * MOUT + c0);
#pragma unroll
    for (int i = 0; i < TR; i++) {
      const float4 xv = *(const float4*)(&Xs[rg * TR + i][k4 * 4]);
      acc[i].x = fmaf(xv.x, wv0.x, acc[i].x); acc[i].y = fmaf(xv.x, wv0.y, acc[i].y);
      acc[i].z = fmaf(xv.x, wv0.z, acc[i].z); acc[i].w = fmaf(xv.x, wv0.w, acc[i].w);
      acc[i].x = fmaf(xv.y, wv1.x, acc[i].x); acc[i].y = fmaf(xv.y, wv1.y, acc[i].y);
      acc[i].z = fmaf(xv.y, wv1.z, acc[i].z); acc[i].w = fmaf(xv.y, wv1.w, acc[i].w);
      acc[i].x = fmaf(xv.z, wv2.x, acc[i].x); acc[i].y = fmaf(xv.z, wv2.y, acc[i].y);
      acc[i].z = fmaf(xv.z, wv2.z, acc[i].z); acc[i].w = fmaf(xv.z, wv2.w, acc[i].w);
      acc[i].x = fmaf(xv.w, wv3.x, acc[i].x); acc[i].y = fmaf(xv.w, wv3.y, acc[i].y);
      acc[i].z = fmaf(xv.w, wv3.z, acc[i].z); acc[i].w = fmaf(xv.w, wv3.w, acc[i].w);
    }
  }
#pragma unroll
  for (int i = 0; i < TR; i++) {
    const int r = row0 + rg * TR + i;
    if (r < n) *(float4*)(H + (size_t)r * MOUT + c0) = acc[i];
  }
}

// ---------------- per-node attention coefficients ----------------
__global__ void alpha64_kernel(const float* __restrict__ H, const float* __restrict__ as,
                               const float* __restrict__ ad, float2* __restrict__ AS,
                               float2* __restrict__ AD, int n) {
  const int wid = threadIdx.x >> 6, lane = threadIdx.x & 63;
  const int node = blockIdx.x * (blockDim.x >> 6) + wid;
  if (node >= n) return;
  const float* hrow = H + (size_t)node * 128;
  const float h0 = hrow[lane], h1 = hrow[64 + lane];
  float s0 = h0 * as[lane], s1 = h1 * as[64 + lane];
  float d0 = h0 * ad[lane], d1 = h1 * ad[64 + lane];
#pragma unroll
  for (int off = 32; off >= 1; off >>= 1) {
    s0 += __shfl_xor(s0, off); s1 += __shfl_xor(s1, off);
    d0 += __shfl_xor(d0, off); d1 += __shfl_xor(d1, off);
  }
  if (lane == 0) { AS[node] = make_float2(s0, s1); AD[node] = make_float2(d0, d1); }
}

__global__ void alpha16_kernel(const float* __restrict__ H, const float* __restrict__ as,
                               const float* __restrict__ ad, float2* __restrict__ AS,
                               float2* __restrict__ AD, int n) {
  const int wid = threadIdx.x >> 6, lane = threadIdx.x & 63;
  const int node = blockIdx.x * (blockDim.x >> 6) + wid;
  if (node >= n) return;
  float sv = 0.f, dv = 0.f;
  if (lane < 32) {
    const float h = H[(size_t)node * 32 + lane];
    sv = h * as[lane];
    dv = h * ad[lane];
  }
#pragma unroll
  for (int off = 8; off >= 1; off >>= 1) { sv += __shfl_xor(sv, off); dv += __shfl_xor(dv, off); }
  const float s1 = __shfl(sv, 16);
  const float d1 = __shfl(dv, 16);
  if (lane == 0) { AS[node] = make_float2(sv, s1); AD[node] = make_float2(dv, d1); }
}

// ---------------- fused softmax + aggregate (wave-per-node) ----------------
// No max subtraction: e = leaky(as+ad) is O(5) for this data; exp(e)/sum(exp(e))
// is mathematically identical to the max-shifted form and safe in fp32 here.
template<int C, int MODE>
__global__ __launch_bounds__(256) void agg_kernel(
    const float* __restrict__ H, const float2* __restrict__ AS,
    const float2* __restrict__ AD, const int* __restrict__ row_ptr,
    const int* __restrict__ col_src, const float* __restrict__ bias,
    float* __restrict__ OUT) {
  constexpr int CAP = 128;           // cached edges per node (fallback beyond)
  __shared__ int    s_src[4 * CAP];
  __shared__ float2 s_w[4 * CAP];
  const int wid  = threadIdx.x >> 6;
  const int lane = threadIdx.x & 63;
  const int node = blockIdx.x * 4 + wid;
  const int base = wid * CAP;

  const int begin = row_ptr[node];
  const int d = row_ptr[node + 1] - begin;
  const float2 adn = AD[node];

  // ---- pass A: edge-parallel weights (lanes stride edges) ----
  float sum0 = 0.f, sum1 = 0.f;
  for (int j = lane; j < d; j += 64) {
    const int src = col_src[begin + j];
    const float2 a = AS[src];
    float e0 = a.x + adn.x; e0 = (e0 > 0.f) ? e0 : kNEG * e0;
    float e1 = a.y + adn.y; e1 = (e1 > 0.f) ? e1 : kNEG * e1;
    const float w0 = __expf(e0), w1 = __expf(e1);
    if (j < CAP) { s_src[base + j] = src; s_w[base + j] = make_float2(w0, w1); }
    sum0 += w0; sum1 += w1;
  }
#pragma unroll
  for (int off = 32; off >= 1; off >>= 1) {
    sum0 += __shfl_xor(sum0, off);
    sum1 += __shfl_xor(sum1, off);
  }
  const float inv0 = 1.0f / (sum0 + 1e-16f);
  const float inv1 = 1.0f / (sum1 + 1e-16f);
  __syncthreads();   // make per-wave LDS region visible across lanes

  const int dcap = (d < CAP) ? d : CAP;

  if constexpr (MODE == 0) {
    const float inv = (lane < 32) ? inv0 : inv1;
    float accx = 0.f, accy = 0.f;
#pragma unroll 4
    for (int j = 0; j < dcap; j++) {
      const int src = s_src[base + j];
      const float2 wv = s_w[base + j];
      const float w = (lane < 32) ? wv.x : wv.y;
      const float2 v = *(const float2*)(H + (size_t)src * 128 + 2 * lane);
      accx = fmaf(w, v.x, accx);
      accy = fmaf(w, v.y, accy);
    }
    for (int j = CAP; j < d; j++) {
      const int src = col_src[begin + j];
      const float2 a = AS[src];
      float e0 = a.x + adn.x; e0 = (e0 > 0.f) ? e0 : kNEG * e0;
      float e1 = a.y + adn.y; e1 = (e1 > 0.f) ? e1 : kNEG * e1;
      const float w = (lane < 32) ? __expf(e0) : __expf(e1);
      const float2 v = *(const float2*)(H + (size_t)src * 128 + 2 * lane);
      accx = fmaf(w, v.x, accx);
      accy = fmaf(w, v.y, accy);
    }
    accx *= inv; accy *= inv;
    const int ch = 2 * lane;
    float vx = accx + bias[ch];
    float vy = accy + bias[ch + 1];
    vx = (vx > 0.f) ? vx : expm1f(vx);
    vy = (vy > 0.f) ? vy : expm1f(vy);
    *(float2*)(OUT + (size_t)node * 128 + ch) = make_float2(vx, vy);
  } else {
    const int ch = lane & 31;
    const int hsel = (ch >= 16);
    const int esel = lane >> 5;
    const float inv = hsel ? inv1 : inv0;
    float acc = 0.f;
    int j = 0;
    for (; j + 1 < dcap; j += 2) {
      const int jj = j + esel;
      const int src = s_src[base + jj];
      const float2 wv = s_w[base + jj];
      const float w = hsel ? wv.y : wv.x;
      acc = fmaf(w, H[(size_t)src * 32 + ch], acc);
    }
    if (j < dcap && esel == 0) {
      const int src = s_src[base + j];
      const float2 wv = s_w[base + j];
      const float w = hsel ? wv.y : wv.x;
      acc = fmaf(w, H[(size_t)src * 32 + ch], acc);
    }
    if (esel == 0) {
      for (int jt = CAP; jt < d; jt++) {
        const int src = col_src[begin + jt];
        const float2 a = AS[src];
        float e0 = a.x + adn.x; e0 = (e0 > 0.f) ? e0 : kNEG * e0;
        float e1 = a.y + adn.y; e1 = (e1 > 0.f) ? e1 : kNEG * e1;
        const float w = hsel ? __expf(e1) : __expf(e0);
        acc = fmaf(w, H[(size_t)src * 32 + ch], acc);
      }
    }
    acc *= inv;
    acc += __shfl_down(acc, 32);
    const float other = __shfl(acc, lane + 16);
    if (lane < 16) OUT[(size_t)node * 16 + lane] = 0.5f * (acc + other) + bias[lane];
  }
}

// ---------------- host launcher ----------------
extern "C" void kernel_launch(void* const* d_in, const int* in_sizes, int n_in,
                              void* d_out, int out_size, void* d_ws, size_t ws_size,
                              hipStream_t stream) {
  const float* x   = (const float*)d_in[0];
  const int*   ei  = (const int*)d_in[1];
  const float* W0  = (const float*)d_in[2];
  const float* as0 = (const float*)d_in[3];
  const float* ad0 = (const float*)d_in[4];
  const float* b0  = (const float*)d_in[5];
  const float* W1  = (const float*)d_in[6];
  const float* as1 = (const float*)d_in[7];
  const float* ad1 = (const float*)d_in[8];
  const float* b1  = (const float*)d_in[9];
  const float* W2  = (const float*)d_in[10];
  const float* as2 = (const float*)d_in[11];
  const float* ad2 = (const float*)d_in[12];
  const float* b2  = (const float*)d_in[13];
  float* out = (float*)d_out;

  size_t off = 0;
  auto alloc = [&](size_t bytes) -> void* {
    void* p = (char*)d_ws + off;
    off += (bytes + 255) & ~(size_t)255;
    return p;
  };
  int*    row_ptr = (int*)alloc(sizeof(int) * (kN + 1));
  int*    bcnt    = (int*)alloc(sizeof(int) * NBUCK);
  int*    bbase   = (int*)alloc(sizeof(int) * (NBUCK + 1));
  int*    bcur    = (int*)alloc(sizeof(int) * NBUCK);
  int*    col_src = (int*)alloc(sizeof(int) * kET);
  float2* AS      = (float2*)alloc(sizeof(float2) * kN);
  float2* AD      = (float2*)alloc(sizeof(float2) * kN);
  float*  bufA    = (float*)alloc(sizeof(float) * (size_t)kN * 128);
  float*  bufB    = (float*)alloc(sizeof(float) * (size_t)kN * 128);
  unsigned* part  = (unsigned*)bufA;   // dead before layer 0 writes bufA
  (void)ws_size; (void)in_sizes; (void)n_in; (void)out_size;

  // ---- CSR build (bucketed counting sort; edge list identical for all layers) ----
  hipMemsetAsync(bcnt, 0, sizeof(int) * NBUCK, stream);
  bucket_hist_kernel<<<PGRID, 256, 0, stream>>>(ei, bcnt);
  bucket_scan_kernel<<<1, 512, 0, stream>>>(bcnt, bbase, bcur);
  partition_kernel<<<PGRID, 256, 0, stream>>>(ei, bcur, part);
  finalize_kernel<<<NBUCK, 256, 0, stream>>>(part, bbase, row_ptr, col_src);

  // ---- layer 0 ----
  transform2_kernel<128, 4><<<(kN + 31) / 32, 256, 0, stream>>>(x, W0, bufA, kN);
  alpha64_kernel<<<(kN + 3) / 4, 256, 0, stream>>>(bufA, as0, ad0, AS, AD, kN);
  agg_kernel<64, 0><<<(kN + 3) / 4, 256, 0, stream>>>(bufA, AS, AD, row_ptr, col_src, b0, bufB);

  // ---- layer 1 ----
  transform2_kernel<128, 4><<<(kN + 31) / 32, 256, 0, stream>>>(bufB, W1, bufA, kN);
  alpha64_kernel<<<(kN + 3) / 4, 256, 0, stream>>>(bufA, as1, ad1, AS, AD, kN);
  agg_kernel<64, 0><<<(kN + 3) / 4, 256, 0, stream>>>(bufA, AS, AD, row_ptr, col_src, b1, bufB);

  // ---- layer 2 ----
  transform2_kernel<32, 1><<<(kN + 31) / 32, 256, 0, stream>>>(bufB, W2, bufA, kN);
  alpha16_kernel<<<(kN + 3) / 4, 256, 0, stream>>>(bufA, as2, ad2, AS, AD, kN);
  agg_kernel<16, 1><<<(kN + 3) / 4, 256, 0, stream>>>(bufA, AS, AD, row_ptr, col_src, b2, out);
}

// Round 4
// 430.385 us; speedup vs baseline: 2.0781x; 1.1060x over previous
//
#include <hip/hip_runtime.h>
#include <cstdint>
#include <cstddef>

// ---------------- problem constants ----------------
constexpr int kN   = 50000;            // nodes
constexpr int kE   = 1600000;          // edges (before self loops)
constexpr int kET  = kE + kN;          // total edges incl self loops
constexpr float kNEG = 0.2f;
constexpr int NBUCK = (kN + 127) / 128;        // 391 buckets of 128 dst nodes
constexpr int PCHUNK = 8192;                   // edges per partition block
constexpr int PGRID = (kET + PCHUNK - 1) / PCHUNK;

// ---------------- CSR build: bucketed counting sort ----------------
__global__ __launch_bounds__(256) void bucket_hist_kernel(const int* __restrict__ ei,
                                                          int* __restrict__ gcnt) {
  __shared__ int h[NBUCK];
  const int t = threadIdx.x;
  for (int i = t; i < NBUCK; i += 256) h[i] = 0;
  __syncthreads();
  const int c0 = blockIdx.x * PCHUNK;
  const int cend = (c0 + PCHUNK < kET) ? c0 + PCHUNK : kET;
  for (int i = c0 + t; i < cend; i += 256) {
    const int dst = (i < kE) ? ei[kE + i] : (i - kE);
    atomicAdd(&h[dst >> 7], 1);
  }
  __syncthreads();
  for (int i = t; i < NBUCK; i += 256) if (h[i]) atomicAdd(&gcnt[i], h[i]);
}

__global__ __launch_bounds__(512) void bucket_scan_kernel(const int* __restrict__ gcnt,
                                                          int* __restrict__ base,
                                                          int* __restrict__ cursor) {
  __shared__ int s[512];
  const int t = threadIdx.x;
  const int myc = (t < NBUCK) ? gcnt[t] : 0;
  s[t] = myc;
  __syncthreads();
  for (int off = 1; off < 512; off <<= 1) {
    const int v = (t >= off) ? s[t - off] : 0;
    __syncthreads();
    s[t] += v;
    __syncthreads();
  }
  if (t < NBUCK) {
    const int excl = s[t] - myc;
    base[t] = excl;
    cursor[t] = excl;
  }
  if (t == 0) base[NBUCK] = kET;
}

// entry = (dst&127)<<16 | src   (src < 50000 < 2^16... packed in low 16? no:
// src < 50000 needs 16 bits -> fits in 16? 50000 > 65536? No, 50000 < 65536. OK.)
__global__ __launch_bounds__(256) void partition_kernel(const int* __restrict__ ei,
                                                        int* __restrict__ cursor,
                                                        unsigned* __restrict__ part) {
  __shared__ int hist[NBUCK];
  __shared__ int resv[NBUCK];
  __shared__ int lcnt[NBUCK];
  const int t = threadIdx.x;
  for (int i = t; i < NBUCK; i += 256) hist[i] = 0;
  __syncthreads();
  const int c0 = blockIdx.x * PCHUNK;
  const int cend = (c0 + PCHUNK < kET) ? c0 + PCHUNK : kET;
  for (int i = c0 + t; i < cend; i += 256) {
    const int dst = (i < kE) ? ei[kE + i] : (i - kE);
    atomicAdd(&hist[dst >> 7], 1);
  }
  __syncthreads();
  for (int i = t; i < NBUCK; i += 256) {
    lcnt[i] = 0;
    if (hist[i]) resv[i] = atomicAdd(&cursor[i], hist[i]);
  }
  __syncthreads();
  for (int i = c0 + t; i < cend; i += 256) {
    int src, dst;
    if (i < kE) { src = ei[i]; dst = ei[kE + i]; }
    else        { src = i - kE; dst = src; }
    const int b = dst >> 7;
    const int off = atomicAdd(&lcnt[b], 1);
    part[resv[b] + off] = ((unsigned)(dst & 127) << 16) | (unsigned)src;
  }
}

__global__ __launch_bounds__(256) void finalize_kernel(const unsigned* __restrict__ part,
                                                       const int* __restrict__ base,
                                                       int* __restrict__ row_ptr,
                                                       int* __restrict__ col_src) {
  __shared__ int cnt[128];
  __shared__ int sc[128];
  __shared__ int nbase[128];
  const int b = blockIdx.x, t = threadIdx.x;
  const int lo = base[b], hi = base[b + 1];
  if (t < 128) cnt[t] = 0;
  __syncthreads();
  for (int j = lo + t; j < hi; j += 256) atomicAdd(&cnt[part[j] >> 16], 1);
  __syncthreads();
  if (t < 128) sc[t] = cnt[t];
  __syncthreads();
  for (int off = 1; off < 128; off <<= 1) {
    int v = 0;
    if (t < 128 && t >= off) v = sc[t - off];
    __syncthreads();
    if (t < 128) sc[t] += v;
    __syncthreads();
  }
  if (t < 128) {
    nbase[t] = lo + sc[t] - cnt[t];
    const int node = b * 128 + t;
    if (node < kN) row_ptr[node] = nbase[t];
    cnt[t] = 0;
  }
  if (b == 0 && t == 255) row_ptr[kN] = kET;
  __syncthreads();
  for (int j = lo + t; j < hi; j += 256) {
    const unsigned v = part[j];
    const int nl = v >> 16;
    const int pos = nbase[nl] + atomicAdd(&cnt[nl], 1);
    col_src[pos] = (int)(v & 0xffffu);
  }
}

// ---------------- dense transform + fused attention coefficients ----------------
// H = X @ W (X:[n,128], W:[128,MOUT]); AS/AD[n] = per-head dots of H-row with as/ad.
template<int MOUT, int TR>
__global__ __launch_bounds__(256) void transform_kernel(
    const float* __restrict__ X, const float* __restrict__ W,
    const float* __restrict__ asf, const float* __restrict__ adf,
    float* __restrict__ H, float2* __restrict__ AS, float2* __restrict__ AD, int n) {
  constexpr int CG = MOUT / 4;       // col groups of 4
  constexpr int RG = 256 / CG;       // row groups
  constexpr int ROWS = RG * TR;      // rows per block
  __shared__ float Xs[ROWS][132];
  const int t = threadIdx.x;
  const int row0 = blockIdx.x * ROWS;
  for (int i = t; i < ROWS * 32; i += 256) {
    const int r = i >> 5, kc = i & 31;
    float4 v = make_float4(0.f, 0.f, 0.f, 0.f);
    if (row0 + r < n) v = ((const float4*)(X + (size_t)(row0 + r) * 128))[kc];
    *(float4*)(&Xs[r][kc * 4]) = v;
  }
  __syncthreads();
  const int cg = t % CG;
  const int rg = t / CG;
  const int c0 = cg * 4;
  float4 acc[TR];
#pragma unroll
  for (int i = 0; i < TR; i++) acc[i] = make_float4(0.f, 0.f, 0.f, 0.f);
  for (int k4 = 0; k4 < 32; k4++) {
    float4 wv0 = *(const float4*)(W + (size_t)(k4 * 4 + 0) * MOUT + c0);
    float4 wv1 = *(const float4*)(W + (size_t)(k4 * 4 + 1) * MOUT + c0);
    float4 wv2 = *(const float4*)(W + (size_t)(k4 * 4 + 2) * MOUT + c0);
    float4 wv3 = *(const float4*)(W + (size_t)(k4 * 4 + 3) * MOUT + c0);
#pragma unroll
    for (int i = 0; i < TR; i++) {
      const float4 xv = *(const float4*)(&Xs[rg * TR + i][k4 * 4]);
      acc[i].x = fmaf(xv.x, wv0.x, acc[i].x); acc[i].y = fmaf(xv.x, wv0.y, acc[i].y);
      acc[i].z = fmaf(xv.x, wv0.z, acc[i].z); acc[i].w = fmaf(xv.x, wv0.w, acc[i].w);
      acc[i].x = fmaf(xv.y, wv1.x, acc[i].x); acc[i].y = fmaf(xv.y, wv1.y, acc[i].y);
      acc[i].z = fmaf(xv.y, wv1.z, acc[i].z); acc[i].w = fmaf(xv.y, wv1.w, acc[i].w);
      acc[i].x = fmaf(xv.z, wv2.x, acc[i].x); acc[i].y = fmaf(xv.z, wv2.y, acc[i].y);
      acc[i].z = fmaf(xv.z, wv2.z, acc[i].z); acc[i].w = fmaf(xv.z, wv2.w, acc[i].w);
      acc[i].x = fmaf(xv.w, wv3.x, acc[i].x); acc[i].y = fmaf(xv.w, wv3.y, acc[i].y);
      acc[i].z = fmaf(xv.w, wv3.z, acc[i].z); acc[i].w = fmaf(xv.w, wv3.w, acc[i].w);
    }
  }
#pragma unroll
  for (int i = 0; i < TR; i++) {
    const int r = row0 + rg * TR + i;
    if (r < n) *(float4*)(H + (size_t)r * MOUT + c0) = acc[i];
  }
  // ---- fused alpha: per-head dot(h, as), dot(h, ad) via shfl reduce ----
  const float4 av = *(const float4*)(asf + c0);
  const float4 dv = *(const float4*)(adf + c0);
  float sred[TR], dred[TR];
#pragma unroll
  for (int i = 0; i < TR; i++) {
    sred[i] = acc[i].x * av.x + acc[i].y * av.y + acc[i].z * av.z + acc[i].w * av.w;
    dred[i] = acc[i].x * dv.x + acc[i].y * dv.y + acc[i].z * dv.z + acc[i].w * dv.w;
  }
#pragma unroll
  for (int off = 1; off < CG / 2; off <<= 1) {
#pragma unroll
    for (int i = 0; i < TR; i++) {
      sred[i] += __shfl_xor(sred[i], off);
      dred[i] += __shfl_xor(dred[i], off);
    }
  }
  const int lane = t & 63;
#pragma unroll
  for (int i = 0; i < TR; i++) {
    const float s1 = __shfl(sred[i], lane + CG / 2);
    const float d1 = __shfl(dred[i], lane + CG / 2);
    if (cg == 0) {
      const int r = row0 + rg * TR + i;
      if (r < n) { AS[r] = make_float2(sred[i], s1); AD[r] = make_float2(dred[i], d1); }
    }
  }
}

// ---------------- fused softmax + aggregate (wave-per-node) ----------------
// No max subtraction: e = leaky(as+ad) is O(5) for this data; exp(e)/sum(exp(e))
// is mathematically identical to the max-shifted form and safe in fp32 here.
// MODE 0 (C=64): OUT[n,128] = elu(agg + bias); float4 gather, 2 edges/iter.
// MODE 1 (C=16): OUT[n,16]  = mean_heads(agg)+b; float2 gather, 4 edges/iter.
template<int C, int MODE>
__global__ __launch_bounds__(256) void agg_kernel(
    const float* __restrict__ H, const float2* __restrict__ AS,
    const float2* __restrict__ AD, const int* __restrict__ row_ptr,
    const int* __restrict__ col_src, const float* __restrict__ bias,
    float* __restrict__ OUT) {
  constexpr int CAP = 128;           // cached edges per node (fallback beyond)
  __shared__ int    s_src[4 * CAP];
  __shared__ float2 s_w[4 * CAP];
  const int wid  = threadIdx.x >> 6;
  const int lane = threadIdx.x & 63;
  const int node = blockIdx.x * 4 + wid;
  const int base = wid * CAP;

  const int begin = row_ptr[node];
  const int d = row_ptr[node + 1] - begin;
  const float2 adn = AD[node];

  // ---- pass A: edge-parallel weights (lanes stride edges) ----
  float sum0 = 0.f, sum1 = 0.f;
  for (int j = lane; j < d; j += 64) {
    const int src = col_src[begin + j];
    const float2 a = AS[src];
    float e0 = a.x + adn.x; e0 = (e0 > 0.f) ? e0 : kNEG * e0;
    float e1 = a.y + adn.y; e1 = (e1 > 0.f) ? e1 : kNEG * e1;
    const float w0 = __expf(e0), w1 = __expf(e1);
    if (j < CAP) { s_src[base + j] = src; s_w[base + j] = make_float2(w0, w1); }
    sum0 += w0; sum1 += w1;
  }
#pragma unroll
  for (int off = 32; off >= 1; off >>= 1) {
    sum0 += __shfl_xor(sum0, off);
    sum1 += __shfl_xor(sum1, off);
  }
  const float inv0 = 1.0f / (sum0 + 1e-16f);
  const float inv1 = 1.0f / (sum1 + 1e-16f);
  __syncthreads();   // LDS visibility

  const int dcap = (d < CAP) ? d : CAP;

  if constexpr (MODE == 0) {
    // lanes 0-31: even edges; lanes 32-63: odd edges. 4 channels/lane (float4).
    const int e = lane >> 5;        // edge-stream
    const int q = lane & 31;        // channel quad: channels 4q..4q+3
    const int hsel = (q >= 16);     // head of my channels
    const float inv = hsel ? inv1 : inv0;
    float4 acc = make_float4(0.f, 0.f, 0.f, 0.f);
    int j = 0;
#pragma unroll 4
    for (; j + 1 < dcap; j += 2) {
      const int jj = j + e;
      const int src = s_src[base + jj];
      const float2 wv = s_w[base + jj];
      const float w = hsel ? wv.y : wv.x;
      const float4 v = *(const float4*)(H + (size_t)src * 128 + 4 * q);
      acc.x = fmaf(w, v.x, acc.x); acc.y = fmaf(w, v.y, acc.y);
      acc.z = fmaf(w, v.z, acc.z); acc.w = fmaf(w, v.w, acc.w);
    }
    if (j < dcap && e == 0) {       // odd leftover
      const int src = s_src[base + j];
      const float2 wv = s_w[base + j];
      const float w = hsel ? wv.y : wv.x;
      const float4 v = *(const float4*)(H + (size_t)src * 128 + 4 * q);
      acc.x = fmaf(w, v.x, acc.x); acc.y = fmaf(w, v.y, acc.y);
      acc.z = fmaf(w, v.z, acc.z); acc.w = fmaf(w, v.w, acc.w);
    }
    for (int jt = CAP + e; jt < d; jt += 2) {   // rare fallback: recompute
      const int src = col_src[begin + jt];
      const float2 a = AS[src];
      float e0 = a.x + adn.x; e0 = (e0 > 0.f) ? e0 : kNEG * e0;
      float e1 = a.y + adn.y; e1 = (e1 > 0.f) ? e1 : kNEG * e1;
      const float w = hsel ? __expf(e1) : __expf(e0);
      const float4 v = *(const float4*)(H + (size_t)src * 128 + 4 * q);
      acc.x = fmaf(w, v.x, acc.x); acc.y = fmaf(w, v.y, acc.y);
      acc.z = fmaf(w, v.z, acc.z); acc.w = fmaf(w, v.w, acc.w);
    }
    // combine the two edge-streams
    acc.x += __shfl_xor(acc.x, 32); acc.y += __shfl_xor(acc.y, 32);
    acc.z += __shfl_xor(acc.z, 32); acc.w += __shfl_xor(acc.w, 32);
    if (lane < 32) {
      const int ch = 4 * q;
      const float4 bv = *(const float4*)(bias + ch);
      float4 o;
      o.x = acc.x * inv + bv.x; o.y = acc.y * inv + bv.y;
      o.z = acc.z * inv + bv.z; o.w = acc.w * inv + bv.w;
      o.x = (o.x > 0.f) ? o.x : expm1f(o.x);
      o.y = (o.y > 0.f) ? o.y : expm1f(o.y);
      o.z = (o.z > 0.f) ? o.z : expm1f(o.z);
      o.w = (o.w > 0.f) ? o.w : expm1f(o.w);
      *(float4*)(OUT + (size_t)node * 128 + ch) = o;
    }
  } else {
    // 4 edge-streams x 16 lanes; 2 channels/lane (float2). H row = 32 floats.
    const int e = lane >> 4;        // edge-stream 0..3
    const int q = lane & 15;        // channels 2q, 2q+1
    const int hsel = (q >= 8);
    const float inv = hsel ? inv1 : inv0;
    float2 acc = make_float2(0.f, 0.f);
    int j = 0;
    for (; j + 3 < dcap; j += 4) {
      const int jj = j + e;
      const int src = s_src[base + jj];
      const float2 wv = s_w[base + jj];
      const float w = hsel ? wv.y : wv.x;
      const float2 v = *(const float2*)(H + (size_t)src * 32 + 2 * q);
      acc.x = fmaf(w, v.x, acc.x); acc.y = fmaf(w, v.y, acc.y);
    }
    const int rem = dcap - j;
    if (e < rem) {
      const int jj = j + e;
      const int src = s_src[base + jj];
      const float2 wv = s_w[base + jj];
      const float w = hsel ? wv.y : wv.x;
      const float2 v = *(const float2*)(H + (size_t)src * 32 + 2 * q);
      acc.x = fmaf(w, v.x, acc.x); acc.y = fmaf(w, v.y, acc.y);
    }
    for (int jt = CAP + e; jt < d; jt += 4) {   // rare fallback
      const int src = col_src[begin + jt];
      const float2 a = AS[src];
      float e0 = a.x + adn.x; e0 = (e0 > 0.f) ? e0 : kNEG * e0;
      float e1 = a.y + adn.y; e1 = (e1 > 0.f) ? e1 : kNEG * e1;
      const float w = hsel ? __expf(e1) : __expf(e0);
      const float2 v = *(const float2*)(H + (size_t)src * 32 + 2 * q);
      acc.x = fmaf(w, v.x, acc.x); acc.y = fmaf(w, v.y, acc.y);
    }
    // combine 4 edge-streams
    acc.x += __shfl_xor(acc.x, 32); acc.y += __shfl_xor(acc.y, 32);
    acc.x += __shfl_xor(acc.x, 16); acc.y += __shfl_xor(acc.y, 16);
    acc.x *= inv; acc.y *= inv;
    // head mean: channel c pairs with c+16 (q pairs with q+8)
    const float px = __shfl_xor(acc.x, 8);
    const float py = __shfl_xor(acc.y, 8);
    if (lane < 8) {
      const int ch = 2 * q;
      float2 o;
      o.x = 0.5f * (acc.x + px) + bias[ch];
      o.y = 0.5f * (acc.y + py) + bias[ch + 1];
      *(float2*)(OUT + (size_t)node * 16 + ch) = o;
    }
  }
}

// ---------------- host launcher ----------------
extern "C" void kernel_launch(void* const* d_in, const int* in_sizes, int n_in,
                              void* d_out, int out_size, void* d_ws, size_t ws_size,
                              hipStream_t stream) {
  const float* x   = (const float*)d_in[0];
  const int*   ei  = (const int*)d_in[1];
  const float* W0  = (const float*)d_in[2];
  const float* as0 = (const float*)d_in[3];
  const float* ad0 = (const float*)d_in[4];
  const float* b0  = (const float*)d_in[5];
  const float* W1  = (const float*)d_in[6];
  const float* as1 = (const float*)d_in[7];
  const float* ad1 = (const float*)d_in[8];
  const float* b1  = (const float*)d_in[9];
  const float* W2  = (const float*)d_in[10];
  const float* as2 = (const float*)d_in[11];
  const float* ad2 = (const float*)d_in[12];
  const float* b2  = (const float*)d_in[13];
  float* out = (float*)d_out;

  size_t off = 0;
  auto alloc = [&](size_t bytes) -> void* {
    void* p = (char*)d_ws + off;
    off += (bytes + 255) & ~(size_t)255;
    return p;
  };
  int*    row_ptr = (int*)alloc(sizeof(int) * (kN + 1));
  int*    bcnt    = (int*)alloc(sizeof(int) * NBUCK);
  int*    bbase   = (int*)alloc(sizeof(int) * (NBUCK + 1));
  int*    bcur    = (int*)alloc(sizeof(int) * NBUCK);
  int*    col_src = (int*)alloc(sizeof(int) * kET);
  float2* AS      = (float2*)alloc(sizeof(float2) * kN);
  float2* AD      = (float2*)alloc(sizeof(float2) * kN);
  float*  bufA    = (float*)alloc(sizeof(float) * (size_t)kN * 128);
  float*  bufB    = (float*)alloc(sizeof(float) * (size_t)kN * 128);
  unsigned* part  = (unsigned*)bufA;   // dead before layer 0 writes bufA
  (void)ws_size; (void)in_sizes; (void)n_in; (void)out_size;

  // ---- CSR build (bucketed counting sort; edge list identical for all layers) ----
  hipMemsetAsync(bcnt, 0, sizeof(int) * NBUCK, stream);
  bucket_hist_kernel<<<PGRID, 256, 0, stream>>>(ei, bcnt);
  bucket_scan_kernel<<<1, 512, 0, stream>>>(bcnt, bbase, bcur);
  partition_kernel<<<PGRID, 256, 0, stream>>>(ei, bcur, part);
  finalize_kernel<<<NBUCK, 256, 0, stream>>>(part, bbase, row_ptr, col_src);

  // ---- layer 0 ----
  transform_kernel<128, 4><<<(kN + 31) / 32, 256, 0, stream>>>(x, W0, as0, ad0, bufA, AS, AD, kN);
  agg_kernel<64, 0><<<(kN + 3) / 4, 256, 0, stream>>>(bufA, AS, AD, row_ptr, col_src, b0, bufB);

  // ---- layer 1 ----
  transform_kernel<128, 4><<<(kN + 31) / 32, 256, 0, stream>>>(bufB, W1, as1, ad1, bufA, AS, AD, kN);
  agg_kernel<64, 0><<<(kN + 3) / 4, 256, 0, stream>>>(bufA, AS, AD, row_ptr, col_src, b1, bufB);

  // ---- layer 2 ----
  transform_kernel<32, 1><<<(kN + 31) / 32, 256, 0, stream>>>(bufB, W2, as2, ad2, bufA, AS, AD, kN);
  agg_kernel<16, 1><<<(kN + 3) / 4, 256, 0, stream>>>(bufA, AS, AD, row_ptr, col_src, b2, out);
}

// Round 5
// 318.596 us; speedup vs baseline: 2.8072x; 1.3509x over previous
//
#include <hip/hip_runtime.h>
#include <hip/hip_fp16.h>
#include <cstdint>
#include <cstddef>

// ---------------- problem constants ----------------
constexpr int kN   = 50000;            // nodes
constexpr int kE   = 1600000;          // edges (before self loops)
constexpr int kET  = kE + kN;          // total edges incl self loops
constexpr float kNEG = 0.2f;
constexpr int NBUCK = (kN + 127) / 128;        // 391 buckets of 128 dst nodes
constexpr int PCHUNK = 8192;                   // edges per partition block
constexpr int PGRID = (kET + PCHUNK - 1) / PCHUNK;

// ---------------- CSR build: bucketed counting sort ----------------
__global__ __launch_bounds__(256) void bucket_hist_kernel(const int* __restrict__ ei,
                                                          int* __restrict__ gcnt) {
  __shared__ int h[NBUCK];
  const int t = threadIdx.x;
  for (int i = t; i < NBUCK; i += 256) h[i] = 0;
  __syncthreads();
  const int c0 = blockIdx.x * PCHUNK;
  const int cend = (c0 + PCHUNK < kET) ? c0 + PCHUNK : kET;
  for (int i = c0 + t; i < cend; i += 256) {
    const int dst = (i < kE) ? ei[kE + i] : (i - kE);
    atomicAdd(&h[dst >> 7], 1);
  }
  __syncthreads();
  for (int i = t; i < NBUCK; i += 256) if (h[i]) atomicAdd(&gcnt[i], h[i]);
}

__global__ __launch_bounds__(512) void bucket_scan_kernel(const int* __restrict__ gcnt,
                                                          int* __restrict__ base,
                                                          int* __restrict__ cursor) {
  __shared__ int s[512];
  const int t = threadIdx.x;
  const int myc = (t < NBUCK) ? gcnt[t] : 0;
  s[t] = myc;
  __syncthreads();
  for (int off = 1; off < 512; off <<= 1) {
    const int v = (t >= off) ? s[t - off] : 0;
    __syncthreads();
    s[t] += v;
    __syncthreads();
  }
  if (t < NBUCK) {
    const int excl = s[t] - myc;
    base[t] = excl;
    cursor[t] = excl;
  }
  if (t == 0) base[NBUCK] = kET;
}

// entry = (dst&127)<<16 | src   (src < 50000 < 2^16)
__global__ __launch_bounds__(256) void partition_kernel(const int* __restrict__ ei,
                                                        int* __restrict__ cursor,
                                                        unsigned* __restrict__ part) {
  __shared__ int hist[NBUCK];
  __shared__ int resv[NBUCK];
  __shared__ int lcnt[NBUCK];
  const int t = threadIdx.x;
  for (int i = t; i < NBUCK; i += 256) hist[i] = 0;
  __syncthreads();
  const int c0 = blockIdx.x * PCHUNK;
  const int cend = (c0 + PCHUNK < kET) ? c0 + PCHUNK : kET;
  for (int i = c0 + t; i < cend; i += 256) {
    const int dst = (i < kE) ? ei[kE + i] : (i - kE);
    atomicAdd(&hist[dst >> 7], 1);
  }
  __syncthreads();
  for (int i = t; i < NBUCK; i += 256) {
    lcnt[i] = 0;
    if (hist[i]) resv[i] = atomicAdd(&cursor[i], hist[i]);
  }
  __syncthreads();
  for (int i = c0 + t; i < cend; i += 256) {
    int src, dst;
    if (i < kE) { src = ei[i]; dst = ei[kE + i]; }
    else        { src = i - kE; dst = src; }
    const int b = dst >> 7;
    const int off = atomicAdd(&lcnt[b], 1);
    part[resv[b] + off] = ((unsigned)(dst & 127) << 16) | (unsigned)src;
  }
}

__global__ __launch_bounds__(256) void finalize_kernel(const unsigned* __restrict__ part,
                                                       const int* __restrict__ base,
                                                       int* __restrict__ row_ptr,
                                                       int* __restrict__ col_src) {
  __shared__ int cnt[128];
  __shared__ int sc[128];
  __shared__ int nbase[128];
  const int b = blockIdx.x, t = threadIdx.x;
  const int lo = base[b], hi = base[b + 1];
  if (t < 128) cnt[t] = 0;
  __syncthreads();
  for (int j = lo + t; j < hi; j += 256) atomicAdd(&cnt[part[j] >> 16], 1);
  __syncthreads();
  if (t < 128) sc[t] = cnt[t];
  __syncthreads();
  for (int off = 1; off < 128; off <<= 1) {
    int v = 0;
    if (t < 128 && t >= off) v = sc[t - off];
    __syncthreads();
    if (t < 128) sc[t] += v;
    __syncthreads();
  }
  if (t < 128) {
    nbase[t] = lo + sc[t] - cnt[t];
    const int node = b * 128 + t;
    if (node < kN) row_ptr[node] = nbase[t];
    cnt[t] = 0;
  }
  if (b == 0 && t == 255) row_ptr[kN] = kET;
  __syncthreads();
  for (int j = lo + t; j < hi; j += 256) {
    const unsigned v = part[j];
    const int nl = v >> 16;
    const int pos = nbase[nl] + atomicAdd(&cnt[nl], 1);
    col_src[pos] = (int)(v & 0xffffu);
  }
}

// ---------------- dense transform + fused attention coefficients ----------------
// H2 (fp16) = X @ W (X:[n,128] fp32); AS/AD from fp32 registers (exact).
template<int MOUT, int TR>
__global__ __launch_bounds__(256) void transform_kernel(
    const float* __restrict__ X, const float* __restrict__ W,
    const float* __restrict__ asf, const float* __restrict__ adf,
    __half* __restrict__ H2, float2* __restrict__ AS, float2* __restrict__ AD, int n) {
  constexpr int CG = MOUT / 4;       // col groups of 4
  constexpr int RG = 256 / CG;       // row groups
  constexpr int ROWS = RG * TR;      // rows per block
  __shared__ float Xs[ROWS][132];
  const int t = threadIdx.x;
  const int row0 = blockIdx.x * ROWS;
  for (int i = t; i < ROWS * 32; i += 256) {
    const int r = i >> 5, kc = i & 31;
    float4 v = make_float4(0.f, 0.f, 0.f, 0.f);
    if (row0 + r < n) v = ((const float4*)(X + (size_t)(row0 + r) * 128))[kc];
    *(float4*)(&Xs[r][kc * 4]) = v;
  }
  __syncthreads();
  const int cg = t % CG;
  const int rg = t / CG;
  const int c0 = cg * 4;
  float4 acc[TR];
#pragma unroll
  for (int i = 0; i < TR; i++) acc[i] = make_float4(0.f, 0.f, 0.f, 0.f);
  for (int k4 = 0; k4 < 32; k4++) {
    float4 wv0 = *(const float4*)(W + (size_t)(k4 * 4 + 0) * MOUT + c0);
    float4 wv1 = *(const float4*)(W + (size_t)(k4 * 4 + 1) * MOUT + c0);
    float4 wv2 = *(const float4*)(W + (size_t)(k4 * 4 + 2) * MOUT + c0);
    float4 wv3 = *(const float4*)(W + (size_t)(k4 * 4 + 3) * MOUT + c0);
#pragma unroll
    for (int i = 0; i < TR; i++) {
      const float4 xv = *(const float4*)(&Xs[rg * TR + i][k4 * 4]);
      acc[i].x = fmaf(xv.x, wv0.x, acc[i].x); acc[i].y = fmaf(xv.x, wv0.y, acc[i].y);
      acc[i].z = fmaf(xv.x, wv0.z, acc[i].z); acc[i].w = fmaf(xv.x, wv0.w, acc[i].w);
      acc[i].x = fmaf(xv.y, wv1.x, acc[i].x); acc[i].y = fmaf(xv.y, wv1.y, acc[i].y);
      acc[i].z = fmaf(xv.y, wv1.z, acc[i].z); acc[i].w = fmaf(xv.y, wv1.w, acc[i].w);
      acc[i].x = fmaf(xv.z, wv2.x, acc[i].x); acc[i].y = fmaf(xv.z, wv2.y, acc[i].y);
      acc[i].z = fmaf(xv.z, wv2.z, acc[i].z); acc[i].w = fmaf(xv.z, wv2.w, acc[i].w);
      acc[i].x = fmaf(xv.w, wv3.x, acc[i].x); acc[i].y = fmaf(xv.w, wv3.y, acc[i].y);
      acc[i].z = fmaf(xv.w, wv3.z, acc[i].z); acc[i].w = fmaf(xv.w, wv3.w, acc[i].w);
    }
  }
#pragma unroll
  for (int i = 0; i < TR; i++) {
    const int r = row0 + rg * TR + i;
    if (r < n) {
      union { __half2 h[2]; uint2 u; } pk;
      pk.h[0] = __floats2half2_rn(acc[i].x, acc[i].y);
      pk.h[1] = __floats2half2_rn(acc[i].z, acc[i].w);
      *(uint2*)(H2 + (size_t)r * MOUT + c0) = pk.u;
    }
  }
  // ---- fused alpha: per-head dot(h, as), dot(h, ad) via shfl reduce (fp32) ----
  const float4 av = *(const float4*)(asf + c0);
  const float4 dv = *(const float4*)(adf + c0);
  float sred[TR], dred[TR];
#pragma unroll
  for (int i = 0; i < TR; i++) {
    sred[i] = acc[i].x * av.x + acc[i].y * av.y + acc[i].z * av.z + acc[i].w * av.w;
    dred[i] = acc[i].x * dv.x + acc[i].y * dv.y + acc[i].z * dv.z + acc[i].w * dv.w;
  }
#pragma unroll
  for (int off = 1; off < CG / 2; off <<= 1) {
#pragma unroll
    for (int i = 0; i < TR; i++) {
      sred[i] += __shfl_xor(sred[i], off);
      dred[i] += __shfl_xor(dred[i], off);
    }
  }
  const int lane = t & 63;
#pragma unroll
  for (int i = 0; i < TR; i++) {
    const float s1 = __shfl(sred[i], lane + CG / 2);
    const float d1 = __shfl(dred[i], lane + CG / 2);
    if (cg == 0) {
      const int r = row0 + rg * TR + i;
      if (r < n) { AS[r] = make_float2(sred[i], s1); AD[r] = make_float2(dred[i], d1); }
    }
  }
}

// ---------------- fused softmax + aggregate (wave-per-node, fp16 gather) ----------------
// No max subtraction: e = leaky(as+ad) is O(5) here; exp without shift is exact math.
// MODE 0 (C=64): OUT[n,128]=elu(agg+bias); 16 lanes/edge x 8 ch, 4 edge-streams.
// MODE 1 (C=16): OUT[n,16]=mean_heads(agg)+b; 8 lanes/edge x 4 ch, 8 edge-streams.
template<int C, int MODE>
__global__ __launch_bounds__(256) void agg_kernel(
    const __half* __restrict__ H2, const float2* __restrict__ AS,
    const float2* __restrict__ AD, const int* __restrict__ row_ptr,
    const int* __restrict__ col_src, const float* __restrict__ bias,
    float* __restrict__ OUT) {
  constexpr int CAP = 128;           // cached edges per node (fallback beyond)
  __shared__ int    s_src[4 * CAP];
  __shared__ float2 s_w[4 * CAP];
  const int wid  = threadIdx.x >> 6;
  const int lane = threadIdx.x & 63;
  const int node = blockIdx.x * 4 + wid;
  const int base = wid * CAP;

  const int begin = row_ptr[node];
  const int d = row_ptr[node + 1] - begin;
  const float2 adn = AD[node];

  // ---- pass A: edge-parallel weights ----
  float sum0 = 0.f, sum1 = 0.f;
  for (int j = lane; j < d; j += 64) {
    const int src = col_src[begin + j];
    const float2 a = AS[src];
    float e0 = a.x + adn.x; e0 = (e0 > 0.f) ? e0 : kNEG * e0;
    float e1 = a.y + adn.y; e1 = (e1 > 0.f) ? e1 : kNEG * e1;
    const float w0 = __expf(e0), w1 = __expf(e1);
    if (j < CAP) { s_src[base + j] = src; s_w[base + j] = make_float2(w0, w1); }
    sum0 += w0; sum1 += w1;
  }
#pragma unroll
  for (int off = 32; off >= 1; off >>= 1) {
    sum0 += __shfl_xor(sum0, off);
    sum1 += __shfl_xor(sum1, off);
  }
  const float inv0 = 1.0f / (sum0 + 1e-16f);
  const float inv1 = 1.0f / (sum1 + 1e-16f);
  __syncthreads();   // LDS visibility

  const int dcap = (d < CAP) ? d : CAP;

  if constexpr (MODE == 0) {
    const int e = lane >> 4;        // edge-stream 0..3
    const int q = lane & 15;        // channels 8q..8q+7
    const int hsel = (q >= 8);
    const float inv = hsel ? inv1 : inv0;
    float4 a0 = make_float4(0.f, 0.f, 0.f, 0.f);
    float4 a1 = make_float4(0.f, 0.f, 0.f, 0.f);
    int j = 0;
    for (; j + 3 < dcap; j += 4) {
      const int jj = j + e;
      const int src = s_src[base + jj];
      const float2 wv = s_w[base + jj];
      const float w = hsel ? wv.y : wv.x;
      union { uint4 u; __half2 h[4]; } raw;
      raw.u = *(const uint4*)(H2 + (size_t)src * 128 + 8 * q);
      const float2 f0 = __half22float2(raw.h[0]);
      const float2 f1 = __half22float2(raw.h[1]);
      const float2 f2 = __half22float2(raw.h[2]);
      const float2 f3 = __half22float2(raw.h[3]);
      a0.x = fmaf(w, f0.x, a0.x); a0.y = fmaf(w, f0.y, a0.y);
      a0.z = fmaf(w, f1.x, a0.z); a0.w = fmaf(w, f1.y, a0.w);
      a1.x = fmaf(w, f2.x, a1.x); a1.y = fmaf(w, f2.y, a1.y);
      a1.z = fmaf(w, f3.x, a1.z); a1.w = fmaf(w, f3.y, a1.w);
    }
    const int rem = dcap - j;
    if (e < rem) {
      const int jj = j + e;
      const int src = s_src[base + jj];
      const float2 wv = s_w[base + jj];
      const float w = hsel ? wv.y : wv.x;
      union { uint4 u; __half2 h[4]; } raw;
      raw.u = *(const uint4*)(H2 + (size_t)src * 128 + 8 * q);
      const float2 f0 = __half22float2(raw.h[0]);
      const float2 f1 = __half22float2(raw.h[1]);
      const float2 f2 = __half22float2(raw.h[2]);
      const float2 f3 = __half22float2(raw.h[3]);
      a0.x = fmaf(w, f0.x, a0.x); a0.y = fmaf(w, f0.y, a0.y);
      a0.z = fmaf(w, f1.x, a0.z); a0.w = fmaf(w, f1.y, a0.w);
      a1.x = fmaf(w, f2.x, a1.x); a1.y = fmaf(w, f2.y, a1.y);
      a1.z = fmaf(w, f3.x, a1.z); a1.w = fmaf(w, f3.y, a1.w);
    }
    for (int jt = CAP + e; jt < d; jt += 4) {   // rare fallback: recompute
      const int src = col_src[begin + jt];
      const float2 a = AS[src];
      float e0 = a.x + adn.x; e0 = (e0 > 0.f) ? e0 : kNEG * e0;
      float e1 = a.y + adn.y; e1 = (e1 > 0.f) ? e1 : kNEG * e1;
      const float w = hsel ? __expf(e1) : __expf(e0);
      union { uint4 u; __half2 h[4]; } raw;
      raw.u = *(const uint4*)(H2 + (size_t)src * 128 + 8 * q);
      const float2 f0 = __half22float2(raw.h[0]);
      const float2 f1 = __half22float2(raw.h[1]);
      const float2 f2 = __half22float2(raw.h[2]);
      const float2 f3 = __half22float2(raw.h[3]);
      a0.x = fmaf(w, f0.x, a0.x); a0.y = fmaf(w, f0.y, a0.y);
      a0.z = fmaf(w, f1.x, a0.z); a0.w = fmaf(w, f1.y, a0.w);
      a1.x = fmaf(w, f2.x, a1.x); a1.y = fmaf(w, f2.y, a1.y);
      a1.z = fmaf(w, f3.x, a1.z); a1.w = fmaf(w, f3.y, a1.w);
    }
    // combine 4 edge-streams
#pragma unroll
    for (int off = 32; off >= 16; off >>= 1) {
      a0.x += __shfl_xor(a0.x, off); a0.y += __shfl_xor(a0.y, off);
      a0.z += __shfl_xor(a0.z, off); a0.w += __shfl_xor(a0.w, off);
      a1.x += __shfl_xor(a1.x, off); a1.y += __shfl_xor(a1.y, off);
      a1.z += __shfl_xor(a1.z, off); a1.w += __shfl_xor(a1.w, off);
    }
    if (lane < 16) {
      const int ch = 8 * q;
      const float4 b0v = *(const float4*)(bias + ch);
      const float4 b1v = *(const float4*)(bias + ch + 4);
      float4 o0, o1;
      o0.x = a0.x * inv + b0v.x; o0.y = a0.y * inv + b0v.y;
      o0.z = a0.z * inv + b0v.z; o0.w = a0.w * inv + b0v.w;
      o1.x = a1.x * inv + b1v.x; o1.y = a1.y * inv + b1v.y;
      o1.z = a1.z * inv + b1v.z; o1.w = a1.w * inv + b1v.w;
      o0.x = (o0.x > 0.f) ? o0.x : expm1f(o0.x);
      o0.y = (o0.y > 0.f) ? o0.y : expm1f(o0.y);
      o0.z = (o0.z > 0.f) ? o0.z : expm1f(o0.z);
      o0.w = (o0.w > 0.f) ? o0.w : expm1f(o0.w);
      o1.x = (o1.x > 0.f) ? o1.x : expm1f(o1.x);
      o1.y = (o1.y > 0.f) ? o1.y : expm1f(o1.y);
      o1.z = (o1.z > 0.f) ? o1.z : expm1f(o1.z);
      o1.w = (o1.w > 0.f) ? o1.w : expm1f(o1.w);
      *(float4*)(OUT + (size_t)node * 128 + ch) = o0;
      *(float4*)(OUT + (size_t)node * 128 + ch + 4) = o1;
    }
  } else {
    const int e = lane >> 3;        // edge-stream 0..7
    const int q = lane & 7;         // channels 4q..4q+3
    const int hsel = (q >= 4);
    const float inv = hsel ? inv1 : inv0;
    float4 acc = make_float4(0.f, 0.f, 0.f, 0.f);
    int j = 0;
    for (; j + 7 < dcap; j += 8) {
      const int jj = j + e;
      const int src = s_src[base + jj];
      const float2 wv = s_w[base + jj];
      const float w = hsel ? wv.y : wv.x;
      union { uint2 u; __half2 h[2]; } raw;
      raw.u = *(const uint2*)(H2 + (size_t)src * 32 + 4 * q);
      const float2 f0 = __half22float2(raw.h[0]);
      const float2 f1 = __half22float2(raw.h[1]);
      acc.x = fmaf(w, f0.x, acc.x); acc.y = fmaf(w, f0.y, acc.y);
      acc.z = fmaf(w, f1.x, acc.z); acc.w = fmaf(w, f1.y, acc.w);
    }
    const int rem = dcap - j;
    if (e < rem) {
      const int jj = j + e;
      const int src = s_src[base + jj];
      const float2 wv = s_w[base + jj];
      const float w = hsel ? wv.y : wv.x;
      union { uint2 u; __half2 h[2]; } raw;
      raw.u = *(const uint2*)(H2 + (size_t)src * 32 + 4 * q);
      const float2 f0 = __half22float2(raw.h[0]);
      const float2 f1 = __half22float2(raw.h[1]);
      acc.x = fmaf(w, f0.x, acc.x); acc.y = fmaf(w, f0.y, acc.y);
      acc.z = fmaf(w, f1.x, acc.z); acc.w = fmaf(w, f1.y, acc.w);
    }
    for (int jt = CAP + e; jt < d; jt += 8) {   // rare fallback
      const int src = col_src[begin + jt];
      const float2 a = AS[src];
      float e0 = a.x + adn.x; e0 = (e0 > 0.f) ? e0 : kNEG * e0;
      float e1 = a.y + adn.y; e1 = (e1 > 0.f) ? e1 : kNEG * e1;
      const float w = hsel ? __expf(e1) : __expf(e0);
      union { uint2 u; __half2 h[2]; } raw;
      raw.u = *(const uint2*)(H2 + (size_t)src * 32 + 4 * q);
      const float2 f0 = __half22float2(raw.h[0]);
      const float2 f1 = __half22float2(raw.h[1]);
      acc.x = fmaf(w, f0.x, acc.x); acc.y = fmaf(w, f0.y, acc.y);
      acc.z = fmaf(w, f1.x, acc.z); acc.w = fmaf(w, f1.y, acc.w);
    }
    // combine 8 edge-streams
#pragma unroll
    for (int off = 32; off >= 8; off >>= 1) {
      acc.x += __shfl_xor(acc.x, off); acc.y += __shfl_xor(acc.y, off);
      acc.z += __shfl_xor(acc.z, off); acc.w += __shfl_xor(acc.w, off);
    }
    acc.x *= inv; acc.y *= inv; acc.z *= inv; acc.w *= inv;
    // head mean: q pairs with q+4 (channel c with c+16)
    const float px = __shfl_xor(acc.x, 4);
    const float py = __shfl_xor(acc.y, 4);
    const float pz = __shfl_xor(acc.z, 4);
    const float pw = __shfl_xor(acc.w, 4);
    if (lane < 4) {
      const int ch = 4 * q;
      const float4 bv = *(const float4*)(bias + ch);
      float4 o;
      o.x = 0.5f * (acc.x + px) + bv.x;
      o.y = 0.5f * (acc.y + py) + bv.y;
      o.z = 0.5f * (acc.z + pz) + bv.z;
      o.w = 0.5f * (acc.w + pw) + bv.w;
      *(float4*)(OUT + (size_t)node * 16 + ch) = o;
    }
  }
}

// ---------------- host launcher ----------------
extern "C" void kernel_launch(void* const* d_in, const int* in_sizes, int n_in,
                              void* d_out, int out_size, void* d_ws, size_t ws_size,
                              hipStream_t stream) {
  const float* x   = (const float*)d_in[0];
  const int*   ei  = (const int*)d_in[1];
  const float* W0  = (const float*)d_in[2];
  const float* as0 = (const float*)d_in[3];
  const float* ad0 = (const float*)d_in[4];
  const float* b0  = (const float*)d_in[5];
  const float* W1  = (const float*)d_in[6];
  const float* as1 = (const float*)d_in[7];
  const float* ad1 = (const float*)d_in[8];
  const float* b1  = (const float*)d_in[9];
  const float* W2  = (const float*)d_in[10];
  const float* as2 = (const float*)d_in[11];
  const float* ad2 = (const float*)d_in[12];
  const float* b2  = (const float*)d_in[13];
  float* out = (float*)d_out;

  size_t off = 0;
  auto alloc = [&](size_t bytes) -> void* {
    void* p = (char*)d_ws + off;
    off += (bytes + 255) & ~(size_t)255;
    return p;
  };
  int*    row_ptr = (int*)alloc(sizeof(int) * (kN + 1));
  int*    bcnt    = (int*)alloc(sizeof(int) * NBUCK);
  int*    bbase   = (int*)alloc(sizeof(int) * (NBUCK + 1));
  int*    bcur    = (int*)alloc(sizeof(int) * NBUCK);
  int*    col_src = (int*)alloc(sizeof(int) * kET);
  float2* AS      = (float2*)alloc(sizeof(float2) * kN);
  float2* AD      = (float2*)alloc(sizeof(float2) * kN);
  __half* H2      = (__half*)alloc(sizeof(__half) * (size_t)kN * 128);
  float*  bufB    = (float*)alloc(sizeof(float) * (size_t)kN * 128);
  unsigned* part  = (unsigned*)bufB;   // dead before layer 0 writes bufB
  (void)ws_size; (void)in_sizes; (void)n_in; (void)out_size;

  // ---- CSR build (bucketed counting sort; edge list identical for all layers) ----
  hipMemsetAsync(bcnt, 0, sizeof(int) * NBUCK, stream);
  bucket_hist_kernel<<<PGRID, 256, 0, stream>>>(ei, bcnt);
  bucket_scan_kernel<<<1, 512, 0, stream>>>(bcnt, bbase, bcur);
  partition_kernel<<<PGRID, 256, 0, stream>>>(ei, bcur, part);
  finalize_kernel<<<NBUCK, 256, 0, stream>>>(part, bbase, row_ptr, col_src);

  // ---- layer 0 ----
  transform_kernel<128, 4><<<(kN + 31) / 32, 256, 0, stream>>>(x, W0, as0, ad0, H2, AS, AD, kN);
  agg_kernel<64, 0><<<(kN + 3) / 4, 256, 0, stream>>>(H2, AS, AD, row_ptr, col_src, b0, bufB);

  // ---- layer 1 ----
  transform_kernel<128, 4><<<(kN + 31) / 32, 256, 0, stream>>>(bufB, W1, as1, ad1, H2, AS, AD, kN);
  agg_kernel<64, 0><<<(kN + 3) / 4, 256, 0, stream>>>(H2, AS, AD, row_ptr, col_src, b1, bufB);

  // ---- layer 2 ----
  transform_kernel<32, 1><<<(kN + 31) / 32, 256, 0, stream>>>(bufB, W2, as2, ad2, H2, AS, AD, kN);
  agg_kernel<16, 1><<<(kN + 3) / 4, 256, 0, stream>>>(H2, AS, AD, row_ptr, col_src, b2, out);
}

// Round 6
// 307.077 us; speedup vs baseline: 2.9125x; 1.0375x over previous
//
#include <hip/hip_runtime.h>
#include <hip/hip_fp16.h>
#include <cstdint>
#include <cstddef>
#include <type_traits>

// ---------------- problem constants ----------------
constexpr int kN   = 50000;            // nodes
constexpr int kE   = 1600000;          // edges (before self loops)
constexpr int kET  = kE + kN;          // total edges incl self loops
constexpr float kNEG = 0.2f;
constexpr int NBUCK = (kN + 127) / 128;        // 391 buckets of 128 dst nodes
constexpr int CAPB  = 5120;                    // bucket capacity (mean 4220, +13 sigma)
constexpr int PCHUNK = 8192;                   // edges per partition block
constexpr int PGRID = (kET + PCHUNK - 1) / PCHUNK;

// ---------------- CSR build: single-pass bucketed partition ----------------
// part entry = (dst&127)<<16 | src  (src < 50000 < 2^16); bucket b region: [b*CAPB, b*CAPB+cnt)
__global__ __launch_bounds__(256) void partition_kernel(const int* __restrict__ ei,
                                                        int* __restrict__ bcnt,
                                                        unsigned* __restrict__ part) {
  __shared__ int hist[NBUCK];
  __shared__ int resv[NBUCK];
  __shared__ int lcnt[NBUCK];
  const int t = threadIdx.x;
  for (int i = t; i < NBUCK; i += 256) hist[i] = 0;
  __syncthreads();
  const int c0 = blockIdx.x * PCHUNK;
  const int cend = (c0 + PCHUNK < kET) ? c0 + PCHUNK : kET;
  for (int i = c0 + t; i < cend; i += 256) {
    const int dst = (i < kE) ? ei[kE + i] : (i - kE);
    atomicAdd(&hist[dst >> 7], 1);
  }
  __syncthreads();
  for (int i = t; i < NBUCK; i += 256) {
    lcnt[i] = 0;
    if (hist[i]) resv[i] = i * CAPB + atomicAdd(&bcnt[i], hist[i]);
  }
  __syncthreads();
  for (int i = c0 + t; i < cend; i += 256) {
    int src, dst;
    if (i < kE) { src = ei[i]; dst = ei[kE + i]; }
    else        { src = i - kE; dst = src; }
    const int b = dst >> 7;
    const int off = atomicAdd(&lcnt[b], 1);
    part[resv[b] + off] = ((unsigned)(dst & 127) << 16) | (unsigned)src;
  }
}

// per bucket: node histogram + scan -> row_beg/row_cnt; scatter col_src (L2-local)
__global__ __launch_bounds__(256) void finalize_kernel(const unsigned* __restrict__ part,
                                                       const int* __restrict__ bcnt,
                                                       int* __restrict__ row_beg,
                                                       int* __restrict__ row_cnt,
                                                       int* __restrict__ col_src) {
  __shared__ int cnt[128];
  __shared__ int sc[128];
  __shared__ int nbase[128];
  const int b = blockIdx.x, t = threadIdx.x;
  const int lo = b * CAPB;
  const int hi = lo + bcnt[b];
  if (t < 128) cnt[t] = 0;
  __syncthreads();
  for (int j = lo + t; j < hi; j += 256) atomicAdd(&cnt[part[j] >> 16], 1);
  __syncthreads();
  if (t < 128) sc[t] = cnt[t];
  __syncthreads();
  for (int off = 1; off < 128; off <<= 1) {
    int v = 0;
    if (t < 128 && t >= off) v = sc[t - off];
    __syncthreads();
    if (t < 128) sc[t] += v;
    __syncthreads();
  }
  if (t < 128) {
    const int c = cnt[t];
    nbase[t] = lo + sc[t] - c;
    const int node = b * 128 + t;
    if (node < kN) { row_beg[node] = nbase[t]; row_cnt[node] = c; }
    cnt[t] = 0;
  }
  __syncthreads();
  for (int j = lo + t; j < hi; j += 256) {
    const unsigned v = part[j];
    const int nl = v >> 16;
    const int pos = nbase[nl] + atomicAdd(&cnt[nl], 1);
    col_src[pos] = (int)(v & 0xffffu);
  }
}

// ---------------- dense transform + fused attention coefficients ----------------
// H2 (fp16) = X @ W; AS/AD from fp32 registers. TIN = float (layer 0) or __half.
template<int MOUT, int TR, typename TIN>
__global__ __launch_bounds__(256) void transform_kernel(
    const TIN* __restrict__ X, const float* __restrict__ W,
    const float* __restrict__ asf, const float* __restrict__ adf,
    __half* __restrict__ H2, float2* __restrict__ AS, float2* __restrict__ AD, int n) {
  constexpr int CG = MOUT / 4;       // col groups of 4
  constexpr int RG = 256 / CG;       // row groups
  constexpr int ROWS = RG * TR;      // rows per block
  __shared__ float Xs[ROWS][132];
  const int t = threadIdx.x;
  const int row0 = blockIdx.x * ROWS;
  if constexpr (std::is_same<TIN, float>::value) {
    for (int i = t; i < ROWS * 32; i += 256) {
      const int r = i >> 5, kc = i & 31;
      float4 v = make_float4(0.f, 0.f, 0.f, 0.f);
      if (row0 + r < n) v = ((const float4*)(X + (size_t)(row0 + r) * 128))[kc];
      *(float4*)(&Xs[r][kc * 4]) = v;
    }
  } else {
    for (int i = t; i < ROWS * 16; i += 256) {
      const int r = i >> 4, kc = i & 15;
      union { uint4 u; __half2 h[4]; } raw;
      raw.u = make_uint4(0u, 0u, 0u, 0u);
      if (row0 + r < n) raw.u = *(const uint4*)(X + (size_t)(row0 + r) * 128 + kc * 8);
      const float2 f0 = __half22float2(raw.h[0]);
      const float2 f1 = __half22float2(raw.h[1]);
      const float2 f2 = __half22float2(raw.h[2]);
      const float2 f3 = __half22float2(raw.h[3]);
      *(float4*)(&Xs[r][kc * 8])     = make_float4(f0.x, f0.y, f1.x, f1.y);
      *(float4*)(&Xs[r][kc * 8 + 4]) = make_float4(f2.x, f2.y, f3.x, f3.y);
    }
  }
  __syncthreads();
  const int cg = t % CG;
  const int rg = t / CG;
  const int c0 = cg * 4;
  float4 acc[TR];
#pragma unroll
  for (int i = 0; i < TR; i++) acc[i] = make_float4(0.f, 0.f, 0.f, 0.f);
  for (int k4 = 0; k4 < 32; k4++) {
    float4 wv0 = *(const float4*)(W + (size_t)(k4 * 4 + 0) * MOUT + c0);
    float4 wv1 = *(const float4*)(W + (size_t)(k4 * 4 + 1) * MOUT + c0);
    float4 wv2 = *(const float4*)(W + (size_t)(k4 * 4 + 2) * MOUT + c0);
    float4 wv3 = *(const float4*)(W + (size_t)(k4 * 4 + 3) * MOUT + c0);
#pragma unroll
    for (int i = 0; i < TR; i++) {
      const float4 xv = *(const float4*)(&Xs[rg * TR + i][k4 * 4]);
      acc[i].x = fmaf(xv.x, wv0.x, acc[i].x); acc[i].y = fmaf(xv.x, wv0.y, acc[i].y);
      acc[i].z = fmaf(xv.x, wv0.z, acc[i].z); acc[i].w = fmaf(xv.x, wv0.w, acc[i].w);
      acc[i].x = fmaf(xv.y, wv1.x, acc[i].x); acc[i].y = fmaf(xv.y, wv1.y, acc[i].y);
      acc[i].z = fmaf(xv.y, wv1.z, acc[i].z); acc[i].w = fmaf(xv.y, wv1.w, acc[i].w);
      acc[i].x = fmaf(xv.z, wv2.x, acc[i].x); acc[i].y = fmaf(xv.z, wv2.y, acc[i].y);
      acc[i].z = fmaf(xv.z, wv2.z, acc[i].z); acc[i].w = fmaf(xv.z, wv2.w, acc[i].w);
      acc[i].x = fmaf(xv.w, wv3.x, acc[i].x); acc[i].y = fmaf(xv.w, wv3.y, acc[i].y);
      acc[i].z = fmaf(xv.w, wv3.z, acc[i].z); acc[i].w = fmaf(xv.w, wv3.w, acc[i].w);
    }
  }
#pragma unroll
  for (int i = 0; i < TR; i++) {
    const int r = row0 + rg * TR + i;
    if (r < n) {
      union { __half2 h[2]; uint2 u; } pk;
      pk.h[0] = __floats2half2_rn(acc[i].x, acc[i].y);
      pk.h[1] = __floats2half2_rn(acc[i].z, acc[i].w);
      *(uint2*)(H2 + (size_t)r * MOUT + c0) = pk.u;
    }
  }
  // ---- fused alpha: per-head dot(h, as), dot(h, ad) via shfl reduce (fp32) ----
  const float4 av = *(const float4*)(asf + c0);
  const float4 dv = *(const float4*)(adf + c0);
  float sred[TR], dred[TR];
#pragma unroll
  for (int i = 0; i < TR; i++) {
    sred[i] = acc[i].x * av.x + acc[i].y * av.y + acc[i].z * av.z + acc[i].w * av.w;
    dred[i] = acc[i].x * dv.x + acc[i].y * dv.y + acc[i].z * dv.z + acc[i].w * dv.w;
  }
#pragma unroll
  for (int off = 1; off < CG / 2; off <<= 1) {
#pragma unroll
    for (int i = 0; i < TR; i++) {
      sred[i] += __shfl_xor(sred[i], off);
      dred[i] += __shfl_xor(dred[i], off);
    }
  }
  const int lane = t & 63;
#pragma unroll
  for (int i = 0; i < TR; i++) {
    const float s1 = __shfl(sred[i], lane + CG / 2);
    const float d1 = __shfl(dred[i], lane + CG / 2);
    if (cg == 0) {
      const int r = row0 + rg * TR + i;
      if (r < n) { AS[r] = make_float2(sred[i], s1); AD[r] = make_float2(dred[i], d1); }
    }
  }
}

// ---------------- fused softmax + aggregate (wave-per-node, packed fp16) ----------------
// No max subtraction: e = leaky(as+ad) is O(4) here; exp without shift is exact math.
// MODE 0 (C=64): OUT[n,128]=elu(agg+bias) as TOUT; 16 lanes/edge x 8ch, 4 edge-streams,
//                __hfma2 accumulation flushed to fp32 every 8 edges/lane.
// MODE 1 (C=16): OUT[n,16]=mean_heads(agg)+b (fp32); 8 lanes/edge x 4ch, 8 edge-streams.
template<int C, int MODE, typename TOUT>
__global__ __launch_bounds__(256) void agg_kernel(
    const __half* __restrict__ H2, const float2* __restrict__ AS,
    const float2* __restrict__ AD, const int* __restrict__ row_beg,
    const int* __restrict__ row_cnt, const int* __restrict__ col_src,
    const float* __restrict__ bias, TOUT* __restrict__ OUT) {
  constexpr int CAP = 128;           // cached edges per node (fallback beyond)
  __shared__ int      s_src[4 * CAP];
  __shared__ unsigned s_wh[2][4 * CAP];   // half2(w,w) per head
  const int wid  = threadIdx.x >> 6;
  const int lane = threadIdx.x & 63;
  const int node = blockIdx.x * 4 + wid;
  const int base = wid * CAP;

  const int begin = row_beg[node];
  const int d = row_cnt[node];
  const float2 adn = AD[node];

  // ---- pass A: edge-parallel weights ----
  float sum0 = 0.f, sum1 = 0.f;
  for (int j = lane; j < d; j += 64) {
    const int src = col_src[begin + j];
    const float2 a = AS[src];
    float e0 = a.x + adn.x; e0 = (e0 > 0.f) ? e0 : kNEG * e0;
    float e1 = a.y + adn.y; e1 = (e1 > 0.f) ? e1 : kNEG * e1;
    const float w0 = __expf(e0), w1 = __expf(e1);
    if (j < CAP) {
      s_src[base + j] = src;
      union { __half2 h; unsigned u; } p0, p1;
      p0.h = __half2half2(__float2half_rn(w0));
      p1.h = __half2half2(__float2half_rn(w1));
      s_wh[0][base + j] = p0.u;
      s_wh[1][base + j] = p1.u;
    }
    sum0 += w0; sum1 += w1;
  }
#pragma unroll
  for (int off = 32; off >= 1; off >>= 1) {
    sum0 += __shfl_xor(sum0, off);
    sum1 += __shfl_xor(sum1, off);
  }
  const float inv0 = 1.0f / (sum0 + 1e-16f);
  const float inv1 = 1.0f / (sum1 + 1e-16f);
  __syncthreads();   // LDS visibility

  const int dcap = (d < CAP) ? d : CAP;

  if constexpr (MODE == 0) {
    const int e = lane >> 4;        // edge-stream 0..3
    const int q = lane & 15;        // channels 8q..8q+7
    const int hsel = (q >= 8);
    const float inv = hsel ? inv1 : inv0;
    const unsigned* wrow = &s_wh[hsel][base];
    float4 a0 = make_float4(0.f, 0.f, 0.f, 0.f);
    float4 a1 = make_float4(0.f, 0.f, 0.f, 0.f);
    int j = 0;
    const int dcap4 = dcap & ~3;
    while (j < dcap4) {
      const int jend = (j + 32 < dcap4) ? j + 32 : dcap4;   // 8 edges/lane per chunk
      __half2 hz; *(unsigned*)&hz = 0u;
      __half2 hc0 = hz, hc1 = hz, hc2 = hz, hc3 = hz;
      for (; j < jend; j += 4) {
        const int jj = j + e;
        const int src = s_src[base + jj];
        union { unsigned u; __half2 h; } wv; wv.u = wrow[jj];
        union { uint4 u; __half2 h[4]; } raw;
        raw.u = *(const uint4*)(H2 + (size_t)src * 128 + 8 * q);
        hc0 = __hfma2(wv.h, raw.h[0], hc0);
        hc1 = __hfma2(wv.h, raw.h[1], hc1);
        hc2 = __hfma2(wv.h, raw.h[2], hc2);
        hc3 = __hfma2(wv.h, raw.h[3], hc3);
      }
      float2 f;
      f = __half22float2(hc0); a0.x += f.x; a0.y += f.y;
      f = __half22float2(hc1); a0.z += f.x; a0.w += f.y;
      f = __half22float2(hc2); a1.x += f.x; a1.y += f.y;
      f = __half22float2(hc3); a1.z += f.x; a1.w += f.y;
    }
    const int rem = dcap - dcap4;
    if (e < rem) {                  // tail edges (fp32 path)
      const int jj = dcap4 + e;
      const int src = s_src[base + jj];
      union { unsigned u; __half2 h; } wv; wv.u = wrow[jj];
      const float w = __low2float(wv.h);
      union { uint4 u; __half2 h[4]; } raw;
      raw.u = *(const uint4*)(H2 + (size_t)src * 128 + 8 * q);
      const float2 f0 = __half22float2(raw.h[0]);
      const float2 f1 = __half22float2(raw.h[1]);
      const float2 f2 = __half22float2(raw.h[2]);
      const float2 f3 = __half22float2(raw.h[3]);
      a0.x = fmaf(w, f0.x, a0.x); a0.y = fmaf(w, f0.y, a0.y);
      a0.z = fmaf(w, f1.x, a0.z); a0.w = fmaf(w, f1.y, a0.w);
      a1.x = fmaf(w, f2.x, a1.x); a1.y = fmaf(w, f2.y, a1.y);
      a1.z = fmaf(w, f3.x, a1.z); a1.w = fmaf(w, f3.y, a1.w);
    }
    for (int jt = CAP + e; jt < d; jt += 4) {   // rare fallback: recompute
      const int src = col_src[begin + jt];
      const float2 a = AS[src];
      float e0 = a.x + adn.x; e0 = (e0 > 0.f) ? e0 : kNEG * e0;
      float e1 = a.y + adn.y; e1 = (e1 > 0.f) ? e1 : kNEG * e1;
      const float w = hsel ? __expf(e1) : __expf(e0);
      union { uint4 u; __half2 h[4]; } raw;
      raw.u = *(const uint4*)(H2 + (size_t)src * 128 + 8 * q);
      const float2 f0 = __half22float2(raw.h[0]);
      const float2 f1 = __half22float2(raw.h[1]);
      const float2 f2 = __half22float2(raw.h[2]);
      const float2 f3 = __half22float2(raw.h[3]);
      a0.x = fmaf(w, f0.x, a0.x); a0.y = fmaf(w, f0.y, a0.y);
      a0.z = fmaf(w, f1.x, a0.z); a0.w = fmaf(w, f1.y, a0.w);
      a1.x = fmaf(w, f2.x, a1.x); a1.y = fmaf(w, f2.y, a1.y);
      a1.z = fmaf(w, f3.x, a1.z); a1.w = fmaf(w, f3.y, a1.w);
    }
    // combine 4 edge-streams
#pragma unroll
    for (int off = 32; off >= 16; off >>= 1) {
      a0.x += __shfl_xor(a0.x, off); a0.y += __shfl_xor(a0.y, off);
      a0.z += __shfl_xor(a0.z, off); a0.w += __shfl_xor(a0.w, off);
      a1.x += __shfl_xor(a1.x, off); a1.y += __shfl_xor(a1.y, off);
      a1.z += __shfl_xor(a1.z, off); a1.w += __shfl_xor(a1.w, off);
    }
    if (lane < 16) {
      const int ch = 8 * q;
      const float4 b0v = *(const float4*)(bias + ch);
      const float4 b1v = *(const float4*)(bias + ch + 4);
      float4 o0, o1;
      o0.x = a0.x * inv + b0v.x; o0.y = a0.y * inv + b0v.y;
      o0.z = a0.z * inv + b0v.z; o0.w = a0.w * inv + b0v.w;
      o1.x = a1.x * inv + b1v.x; o1.y = a1.y * inv + b1v.y;
      o1.z = a1.z * inv + b1v.z; o1.w = a1.w * inv + b1v.w;
      o0.x = (o0.x > 0.f) ? o0.x : expm1f(o0.x);
      o0.y = (o0.y > 0.f) ? o0.y : expm1f(o0.y);
      o0.z = (o0.z > 0.f) ? o0.z : expm1f(o0.z);
      o0.w = (o0.w > 0.f) ? o0.w : expm1f(o0.w);
      o1.x = (o1.x > 0.f) ? o1.x : expm1f(o1.x);
      o1.y = (o1.y > 0.f) ? o1.y : expm1f(o1.y);
      o1.z = (o1.z > 0.f) ? o1.z : expm1f(o1.z);
      o1.w = (o1.w > 0.f) ? o1.w : expm1f(o1.w);
      if constexpr (std::is_same<TOUT, __half>::value) {
        union { __half2 h[4]; uint4 u; } pk;
        pk.h[0] = __floats2half2_rn(o0.x, o0.y);
        pk.h[1] = __floats2half2_rn(o0.z, o0.w);
        pk.h[2] = __floats2half2_rn(o1.x, o1.y);
        pk.h[3] = __floats2half2_rn(o1.z, o1.w);
        *(uint4*)(OUT + (size_t)node * 128 + ch) = pk.u;
      } else {
        *(float4*)((float*)OUT + (size_t)node * 128 + ch) = o0;
        *(float4*)((float*)OUT + (size_t)node * 128 + ch + 4) = o1;
      }
    }
  } else {
    const int e = lane >> 3;        // edge-stream 0..7
    const int q = lane & 7;         // channels 4q..4q+3
    const int hsel = (q >= 4);
    const float inv = hsel ? inv1 : inv0;
    const unsigned* wrow = &s_wh[hsel][base];
    __half2 hz; *(unsigned*)&hz = 0u;
    __half2 hc0 = hz, hc1 = hz;     // <=16 edges/lane in fp16 accum (dcap<=128)
    int j = 0;
    const int dcap8 = dcap & ~7;
    for (; j < dcap8; j += 8) {
      const int jj = j + e;
      const int src = s_src[base + jj];
      union { unsigned u; __half2 h; } wv; wv.u = wrow[jj];
      union { uint2 u; __half2 h[2]; } raw;
      raw.u = *(const uint2*)(H2 + (size_t)src * 32 + 4 * q);
      hc0 = __hfma2(wv.h, raw.h[0], hc0);
      hc1 = __hfma2(wv.h, raw.h[1], hc1);
    }
    float4 acc;
    float2 f;
    f = __half22float2(hc0); acc.x = f.x; acc.y = f.y;
    f = __half22float2(hc1); acc.z = f.x; acc.w = f.y;
    const int rem = dcap - dcap8;
    if (e < rem) {                  // tail (fp32)
      const int jj = dcap8 + e;
      const int src = s_src[base + jj];
      union { unsigned u; __half2 h; } wv; wv.u = wrow[jj];
      const float w = __low2float(wv.h);
      union { uint2 u; __half2 h[2]; } raw;
      raw.u = *(const uint2*)(H2 + (size_t)src * 32 + 4 * q);
      const float2 f0 = __half22float2(raw.h[0]);
      const float2 f1 = __half22float2(raw.h[1]);
      acc.x = fmaf(w, f0.x, acc.x); acc.y = fmaf(w, f0.y, acc.y);
      acc.z = fmaf(w, f1.x, acc.z); acc.w = fmaf(w, f1.y, acc.w);
    }
    for (int jt = CAP + e; jt < d; jt += 8) {   // rare fallback
      const int src = col_src[begin + jt];
      const float2 a = AS[src];
      float e0 = a.x + adn.x; e0 = (e0 > 0.f) ? e0 : kNEG * e0;
      float e1 = a.y + adn.y; e1 = (e1 > 0.f) ? e1 : kNEG * e1;
      const float w = hsel ? __expf(e1) : __expf(e0);
      union { uint2 u; __half2 h[2]; } raw;
      raw.u = *(const uint2*)(H2 + (size_t)src * 32 + 4 * q);
      const float2 f0 = __half22float2(raw.h[0]);
      const float2 f1 = __half22float2(raw.h[1]);
      acc.x = fmaf(w, f0.x, acc.x); acc.y = fmaf(w, f0.y, acc.y);
      acc.z = fmaf(w, f1.x, acc.z); acc.w = fmaf(w, f1.y, acc.w);
    }
    // combine 8 edge-streams
#pragma unroll
    for (int off = 32; off >= 8; off >>= 1) {
      acc.x += __shfl_xor(acc.x, off); acc.y += __shfl_xor(acc.y, off);
      acc.z += __shfl_xor(acc.z, off); acc.w += __shfl_xor(acc.w, off);
    }
    acc.x *= inv; acc.y *= inv; acc.z *= inv; acc.w *= inv;
    // head mean: q pairs with q+4 (channel c with c+16)
    const float px = __shfl_xor(acc.x, 4);
    const float py = __shfl_xor(acc.y, 4);
    const float pz = __shfl_xor(acc.z, 4);
    const float pw = __shfl_xor(acc.w, 4);
    if (lane < 4) {
      const int ch = 4 * q;
      const float4 bv = *(const float4*)(bias + ch);
      float4 o;
      o.x = 0.5f * (acc.x + px) + bv.x;
      o.y = 0.5f * (acc.y + py) + bv.y;
      o.z = 0.5f * (acc.z + pz) + bv.z;
      o.w = 0.5f * (acc.w + pw) + bv.w;
      *(float4*)((float*)OUT + (size_t)node * 16 + ch) = o;
    }
  }
}

// ---------------- host launcher ----------------
extern "C" void kernel_launch(void* const* d_in, const int* in_sizes, int n_in,
                              void* d_out, int out_size, void* d_ws, size_t ws_size,
                              hipStream_t stream) {
  const float* x   = (const float*)d_in[0];
  const int*   ei  = (const int*)d_in[1];
  const float* W0  = (const float*)d_in[2];
  const float* as0 = (const float*)d_in[3];
  const float* ad0 = (const float*)d_in[4];
  const float* b0  = (const float*)d_in[5];
  const float* W1  = (const float*)d_in[6];
  const float* as1 = (const float*)d_in[7];
  const float* ad1 = (const float*)d_in[8];
  const float* b1  = (const float*)d_in[9];
  const float* W2  = (const float*)d_in[10];
  const float* as2 = (const float*)d_in[11];
  const float* ad2 = (const float*)d_in[12];
  const float* b2  = (const float*)d_in[13];
  float* out = (float*)d_out;

  size_t off = 0;
  auto alloc = [&](size_t bytes) -> void* {
    void* p = (char*)d_ws + off;
    off += (bytes + 255) & ~(size_t)255;
    return p;
  };
  int*    row_beg = (int*)alloc(sizeof(int) * kN);
  int*    row_cnt = (int*)alloc(sizeof(int) * kN);
  int*    bcnt    = (int*)alloc(sizeof(int) * NBUCK);
  int*    col_src = (int*)alloc(sizeof(int) * (size_t)NBUCK * CAPB);
  float2* AS      = (float2*)alloc(sizeof(float2) * kN);
  float2* AD      = (float2*)alloc(sizeof(float2) * kN);
  __half* H2      = (__half*)alloc(sizeof(__half) * (size_t)kN * 128);
  __half* actA    = (__half*)alloc(sizeof(__half) * (size_t)kN * 128);
  __half* actB    = (__half*)alloc(sizeof(__half) * (size_t)kN * 128);
  unsigned* part  = (unsigned*)actA;   // 8MB <= 12.8MB; dead before layer-0 agg writes actA
  (void)ws_size; (void)in_sizes; (void)n_in; (void)out_size;

  // ---- CSR build (single-pass bucketed partition; edge list identical for all layers) ----
  hipMemsetAsync(bcnt, 0, sizeof(int) * NBUCK, stream);
  partition_kernel<<<PGRID, 256, 0, stream>>>(ei, bcnt, part);
  finalize_kernel<<<NBUCK, 256, 0, stream>>>(part, bcnt, row_beg, row_cnt, col_src);

  // ---- layer 0 ----
  transform_kernel<128, 4, float><<<(kN + 31) / 32, 256, 0, stream>>>(x, W0, as0, ad0, H2, AS, AD, kN);
  agg_kernel<64, 0, __half><<<(kN + 3) / 4, 256, 0, stream>>>(H2, AS, AD, row_beg, row_cnt, col_src, b0, actA);

  // ---- layer 1 ----
  transform_kernel<128, 4, __half><<<(kN + 31) / 32, 256, 0, stream>>>(actA, W1, as1, ad1, H2, AS, AD, kN);
  agg_kernel<64, 0, __half><<<(kN + 3) / 4, 256, 0, stream>>>(H2, AS, AD, row_beg, row_cnt, col_src, b1, actB);

  // ---- layer 2 ----
  transform_kernel<32, 1, __half><<<(kN + 31) / 32, 256, 0, stream>>>(actB, W2, as2, ad2, H2, AS, AD, kN);
  agg_kernel<16, 1, float><<<(kN + 3) / 4, 256, 0, stream>>>(H2, AS, AD, row_beg, row_cnt, col_src, b2, out);
}

// Round 7
// 300.744 us; speedup vs baseline: 2.9738x; 1.0211x over previous
//
#include <hip/hip_runtime.h>
#include <hip/hip_fp16.h>
#include <cstdint>
#include <cstddef>
#include <type_traits>

// ---------------- problem constants ----------------
constexpr int kN   = 50000;            // nodes
constexpr int kE   = 1600000;          // edges (before self loops)
constexpr int kET  = kE + kN;          // total edges incl self loops
constexpr float kNEG = 0.2f;
constexpr int NBUCK = (kN + 127) / 128;        // 391 buckets of 128 dst nodes
constexpr int CAPB  = 5120;                    // bucket capacity (mean 4220, +13 sigma)
constexpr int PCHUNK = 4096;                   // edges per partition block
constexpr int PGRID = (kET + PCHUNK - 1) / PCHUNK;

// ---------------- CSR build: single-pass bucketed partition ----------------
// part entry = (dst&127)<<16 | src  (src < 50000 < 2^16); bucket b region: [b*CAPB, b*CAPB+cnt)
__global__ __launch_bounds__(256) void partition_kernel(const int* __restrict__ ei,
                                                        int* __restrict__ bcnt,
                                                        unsigned* __restrict__ part) {
  __shared__ int hist[NBUCK];
  __shared__ int resv[NBUCK];
  __shared__ int lcnt[NBUCK];
  const int t = threadIdx.x;
  for (int i = t; i < NBUCK; i += 256) hist[i] = 0;
  __syncthreads();
  const int c0 = blockIdx.x * PCHUNK;
  const int cend = (c0 + PCHUNK < kET) ? c0 + PCHUNK : kET;
  for (int i = c0 + t; i < cend; i += 256) {
    const int dst = (i < kE) ? ei[kE + i] : (i - kE);
    atomicAdd(&hist[dst >> 7], 1);
  }
  __syncthreads();
  for (int i = t; i < NBUCK; i += 256) {
    lcnt[i] = 0;
    if (hist[i]) resv[i] = i * CAPB + atomicAdd(&bcnt[i], hist[i]);
  }
  __syncthreads();
  for (int i = c0 + t; i < cend; i += 256) {
    int src, dst;
    if (i < kE) { src = ei[i]; dst = ei[kE + i]; }
    else        { src = i - kE; dst = src; }
    const int b = dst >> 7;
    const int off = atomicAdd(&lcnt[b], 1);
    part[resv[b] + off] = ((unsigned)(dst & 127) << 16) | (unsigned)src;
  }
}

// per bucket: node histogram + scan -> row_beg/row_cnt; scatter col_src (L2-local)
__global__ __launch_bounds__(256) void finalize_kernel(const unsigned* __restrict__ part,
                                                       const int* __restrict__ bcnt,
                                                       int* __restrict__ row_beg,
                                                       int* __restrict__ row_cnt,
                                                       int* __restrict__ col_src) {
  __shared__ int cnt[128];
  __shared__ int sc[128];
  __shared__ int nbase[128];
  const int b = blockIdx.x, t = threadIdx.x;
  const int lo = b * CAPB;
  const int hi = lo + bcnt[b];
  if (t < 128) cnt[t] = 0;
  __syncthreads();
  for (int j = lo + t; j < hi; j += 256) atomicAdd(&cnt[part[j] >> 16], 1);
  __syncthreads();
  if (t < 128) sc[t] = cnt[t];
  __syncthreads();
  for (int off = 1; off < 128; off <<= 1) {
    int v = 0;
    if (t < 128 && t >= off) v = sc[t - off];
    __syncthreads();
    if (t < 128) sc[t] += v;
    __syncthreads();
  }
  if (t < 128) {
    const int c = cnt[t];
    nbase[t] = lo + sc[t] - c;
    const int node = b * 128 + t;
    if (node < kN) { row_beg[node] = nbase[t]; row_cnt[node] = c; }
    cnt[t] = 0;
  }
  __syncthreads();
  for (int j = lo + t; j < hi; j += 256) {
    const unsigned v = part[j];
    const int nl = v >> 16;
    const int pos = nbase[nl] + atomicAdd(&cnt[nl], 1);
    col_src[pos] = (int)(v & 0xffffu);
  }
}

// ---------------- dense transform + fused attention coefficients ----------------
// H2 (fp16) = X @ W; AS/AD from fp32 registers. TIN = float (layer 0) or __half.
template<int MOUT, int TR, typename TIN>
__global__ __launch_bounds__(256) void transform_kernel(
    const TIN* __restrict__ X, const float* __restrict__ W,
    const float* __restrict__ asf, const float* __restrict__ adf,
    __half* __restrict__ H2, float2* __restrict__ AS, float2* __restrict__ AD, int n) {
  constexpr int CG = MOUT / 4;       // col groups of 4
  constexpr int RG = 256 / CG;       // row groups
  constexpr int ROWS = RG * TR;      // rows per block
  __shared__ float Xs[ROWS][132];
  const int t = threadIdx.x;
  const int row0 = blockIdx.x * ROWS;
  if constexpr (std::is_same<TIN, float>::value) {
    for (int i = t; i < ROWS * 32; i += 256) {
      const int r = i >> 5, kc = i & 31;
      float4 v = make_float4(0.f, 0.f, 0.f, 0.f);
      if (row0 + r < n) v = ((const float4*)(X + (size_t)(row0 + r) * 128))[kc];
      *(float4*)(&Xs[r][kc * 4]) = v;
    }
  } else {
    for (int i = t; i < ROWS * 16; i += 256) {
      const int r = i >> 4, kc = i & 15;
      union { uint4 u; __half2 h[4]; } raw;
      raw.u = make_uint4(0u, 0u, 0u, 0u);
      if (row0 + r < n) raw.u = *(const uint4*)(X + (size_t)(row0 + r) * 128 + kc * 8);
      const float2 f0 = __half22float2(raw.h[0]);
      const float2 f1 = __half22float2(raw.h[1]);
      const float2 f2 = __half22float2(raw.h[2]);
      const float2 f3 = __half22float2(raw.h[3]);
      *(float4*)(&Xs[r][kc * 8])     = make_float4(f0.x, f0.y, f1.x, f1.y);
      *(float4*)(&Xs[r][kc * 8 + 4]) = make_float4(f2.x, f2.y, f3.x, f3.y);
    }
  }
  __syncthreads();
  const int cg = t % CG;
  const int rg = t / CG;
  const int c0 = cg * 4;
  float4 acc[TR];
#pragma unroll
  for (int i = 0; i < TR; i++) acc[i] = make_float4(0.f, 0.f, 0.f, 0.f);
  for (int k4 = 0; k4 < 32; k4++) {
    float4 wv0 = *(const float4*)(W + (size_t)(k4 * 4 + 0) * MOUT + c0);
    float4 wv1 = *(const float4*)(W + (size_t)(k4 * 4 + 1) * MOUT + c0);
    float4 wv2 = *(const float4*)(W + (size_t)(k4 * 4 + 2) * MOUT + c0);
    float4 wv3 = *(const float4*)(W + (size_t)(k4 * 4 + 3) * MOUT + c0);
#pragma unroll
    for (int i = 0; i < TR; i++) {
      const float4 xv = *(const float4*)(&Xs[rg * TR + i][k4 * 4]);
      acc[i].x = fmaf(xv.x, wv0.x, acc[i].x); acc[i].y = fmaf(xv.x, wv0.y, acc[i].y);
      acc[i].z = fmaf(xv.x, wv0.z, acc[i].z); acc[i].w = fmaf(xv.x, wv0.w, acc[i].w);
      acc[i].x = fmaf(xv.y, wv1.x, acc[i].x); acc[i].y = fmaf(xv.y, wv1.y, acc[i].y);
      acc[i].z = fmaf(xv.y, wv1.z, acc[i].z); acc[i].w = fmaf(xv.y, wv1.w, acc[i].w);
      acc[i].x = fmaf(xv.z, wv2.x, acc[i].x); acc[i].y = fmaf(xv.z, wv2.y, acc[i].y);
      acc[i].z = fmaf(xv.z, wv2.z, acc[i].z); acc[i].w = fmaf(xv.z, wv2.w, acc[i].w);
      acc[i].x = fmaf(xv.w, wv3.x, acc[i].x); acc[i].y = fmaf(xv.w, wv3.y, acc[i].y);
      acc[i].z = fmaf(xv.w, wv3.z, acc[i].z); acc[i].w = fmaf(xv.w, wv3.w, acc[i].w);
    }
  }
#pragma unroll
  for (int i = 0; i < TR; i++) {
    const int r = row0 + rg * TR + i;
    if (r < n) {
      union { __half2 h[2]; uint2 u; } pk;
      pk.h[0] = __floats2half2_rn(acc[i].x, acc[i].y);
      pk.h[1] = __floats2half2_rn(acc[i].z, acc[i].w);
      *(uint2*)(H2 + (size_t)r * MOUT + c0) = pk.u;
    }
  }
  // ---- fused alpha: per-head dot(h, as), dot(h, ad) via shfl reduce (fp32) ----
  const float4 av = *(const float4*)(asf + c0);
  const float4 dv = *(const float4*)(adf + c0);
  float sred[TR], dred[TR];
#pragma unroll
  for (int i = 0; i < TR; i++) {
    sred[i] = acc[i].x * av.x + acc[i].y * av.y + acc[i].z * av.z + acc[i].w * av.w;
    dred[i] = acc[i].x * dv.x + acc[i].y * dv.y + acc[i].z * dv.z + acc[i].w * dv.w;
  }
#pragma unroll
  for (int off = 1; off < CG / 2; off <<= 1) {
#pragma unroll
    for (int i = 0; i < TR; i++) {
      sred[i] += __shfl_xor(sred[i], off);
      dred[i] += __shfl_xor(dred[i], off);
    }
  }
  const int lane = t & 63;
#pragma unroll
  for (int i = 0; i < TR; i++) {
    const float s1 = __shfl(sred[i], lane + CG / 2);
    const float d1 = __shfl(dred[i], lane + CG / 2);
    if (cg == 0) {
      const int r = row0 + rg * TR + i;
      if (r < n) { AS[r] = make_float2(sred[i], s1); AD[r] = make_float2(dred[i], d1); }
    }
  }
}

// ---------------- fused softmax + aggregate (barrier-free, wave-per-node) ----------------
// Weights live in REGISTERS (one edge per lane, d<=64 fast path); pass B fetches
// (src, packed-w) from owning lanes via dynamic __shfl (ds_bpermute) — no LDS, no
// __syncthreads, waves fully independent. d>64 (prob ~1e-7) exact-recompute fallback.
// No max subtraction: e = leaky(as+ad) is O(4) here; exp without shift is exact math.
// MODE 0 (C=64): OUT[n,128]=elu(agg+bias) as TOUT; 16 lanes/edge x 8ch, 4 edge-streams.
// MODE 1 (C=16): OUT[n,16]=mean_heads(agg)+b (fp32); 8 lanes/edge x 4ch, 8 edge-streams.
template<int C, int MODE, typename TOUT>
__global__ __launch_bounds__(256) void agg_kernel(
    const __half* __restrict__ H2, const float2* __restrict__ AS,
    const float2* __restrict__ AD, const int* __restrict__ row_beg,
    const int* __restrict__ row_cnt, const int* __restrict__ col_src,
    const float* __restrict__ bias, TOUT* __restrict__ OUT) {
  const int wid  = threadIdx.x >> 6;
  const int lane = threadIdx.x & 63;
  const int node = blockIdx.x * 4 + wid;

  const int begin = row_beg[node];
  const int d = row_cnt[node];
  const float2 adn = AD[node];

  // ---- pass A: one edge per lane, weights in registers ----
  int srcv = 0;
  unsigned pkw = 0;                 // half2: low = w_head0, high = w_head1
  float sum0 = 0.f, sum1 = 0.f;
  if (lane < d) {
    srcv = col_src[begin + lane];
    const float2 a = AS[srcv];
    float e0 = a.x + adn.x; e0 = (e0 > 0.f) ? e0 : kNEG * e0;
    float e1 = a.y + adn.y; e1 = (e1 > 0.f) ? e1 : kNEG * e1;
    sum0 = __expf(e0); sum1 = __expf(e1);
    const __half2 ph = __floats2half2_rn(sum0, sum1);
    pkw = *(const unsigned*)&ph;
  }
  for (int j = 64 + lane; j < d; j += 64) {    // ultra-rare d>64 tail (sums only)
    const int s = col_src[begin + j];
    const float2 a = AS[s];
    float e0 = a.x + adn.x; e0 = (e0 > 0.f) ? e0 : kNEG * e0;
    float e1 = a.y + adn.y; e1 = (e1 > 0.f) ? e1 : kNEG * e1;
    sum0 += __expf(e0); sum1 += __expf(e1);
  }
#pragma unroll
  for (int off = 32; off >= 1; off >>= 1) {
    sum0 += __shfl_xor(sum0, off);
    sum1 += __shfl_xor(sum1, off);
  }
  const float inv0 = 1.0f / (sum0 + 1e-16f);
  const float inv1 = 1.0f / (sum1 + 1e-16f);

  const int dr = (d < 64) ? d : 64;            // register-held edges

  if constexpr (MODE == 0) {
    const int e = lane >> 4;        // edge-stream 0..3
    const int q = lane & 15;        // channels 8q..8q+7
    const int hsel = (q >= 8);
    const unsigned sel = hsel ? 0x03020302u : 0x01000100u;  // replicate my head's half
    const float inv = hsel ? inv1 : inv0;
    float4 a0 = make_float4(0.f, 0.f, 0.f, 0.f);
    float4 a1 = make_float4(0.f, 0.f, 0.f, 0.f);
    int j = 0;
    while (j < dr) {
      const int jend = (j + 32 < dr) ? j + 32 : dr;   // <=8 edges/lane per fp16 chunk
      __half2 hz; *(unsigned*)&hz = 0u;
      __half2 hc0 = hz, hc1 = hz, hc2 = hz, hc3 = hz;
      for (; j < jend; j += 4) {
        const int jj = j + e;                          // jj <= 63 always
        const int s = __shfl(srcv, jj);
        const unsigned pw = __shfl((int)pkw, jj);      // 0 for jj >= d -> contributes 0
        union { unsigned u; __half2 h; } wv;
        wv.u = __builtin_amdgcn_perm(pw, pw, sel);     // half2(w,w) of my head
        union { uint4 u; __half2 h[4]; } raw;
        raw.u = *(const uint4*)(H2 + (size_t)s * 128 + 8 * q);
        hc0 = __hfma2(wv.h, raw.h[0], hc0);
        hc1 = __hfma2(wv.h, raw.h[1], hc1);
        hc2 = __hfma2(wv.h, raw.h[2], hc2);
        hc3 = __hfma2(wv.h, raw.h[3], hc3);
      }
      float2 f;
      f = __half22float2(hc0); a0.x += f.x; a0.y += f.y;
      f = __half22float2(hc1); a0.z += f.x; a0.w += f.y;
      f = __half22float2(hc2); a1.x += f.x; a1.y += f.y;
      f = __half22float2(hc3); a1.z += f.x; a1.w += f.y;
    }
    for (int jt = 64 + e; jt < d; jt += 4) {   // ultra-rare fallback: exact recompute
      const int s = col_src[begin + jt];
      const float2 a = AS[s];
      float e0 = a.x + adn.x; e0 = (e0 > 0.f) ? e0 : kNEG * e0;
      float e1 = a.y + adn.y; e1 = (e1 > 0.f) ? e1 : kNEG * e1;
      const float w = hsel ? __expf(e1) : __expf(e0);
      union { uint4 u; __half2 h[4]; } raw;
      raw.u = *(const uint4*)(H2 + (size_t)s * 128 + 8 * q);
      const float2 f0 = __half22float2(raw.h[0]);
      const float2 f1 = __half22float2(raw.h[1]);
      const float2 f2 = __half22float2(raw.h[2]);
      const float2 f3 = __half22float2(raw.h[3]);
      a0.x = fmaf(w, f0.x, a0.x); a0.y = fmaf(w, f0.y, a0.y);
      a0.z = fmaf(w, f1.x, a0.z); a0.w = fmaf(w, f1.y, a0.w);
      a1.x = fmaf(w, f2.x, a1.x); a1.y = fmaf(w, f2.y, a1.y);
      a1.z = fmaf(w, f3.x, a1.z); a1.w = fmaf(w, f3.y, a1.w);
    }
    // combine 4 edge-streams
#pragma unroll
    for (int off = 32; off >= 16; off >>= 1) {
      a0.x += __shfl_xor(a0.x, off); a0.y += __shfl_xor(a0.y, off);
      a0.z += __shfl_xor(a0.z, off); a0.w += __shfl_xor(a0.w, off);
      a1.x += __shfl_xor(a1.x, off); a1.y += __shfl_xor(a1.y, off);
      a1.z += __shfl_xor(a1.z, off); a1.w += __shfl_xor(a1.w, off);
    }
    if (lane < 16) {
      const int ch = 8 * q;
      const float4 b0v = *(const float4*)(bias + ch);
      const float4 b1v = *(const float4*)(bias + ch + 4);
      float4 o0, o1;
      o0.x = a0.x * inv + b0v.x; o0.y = a0.y * inv + b0v.y;
      o0.z = a0.z * inv + b0v.z; o0.w = a0.w * inv + b0v.w;
      o1.x = a1.x * inv + b1v.x; o1.y = a1.y * inv + b1v.y;
      o1.z = a1.z * inv + b1v.z; o1.w = a1.w * inv + b1v.w;
      o0.x = (o0.x > 0.f) ? o0.x : expm1f(o0.x);
      o0.y = (o0.y > 0.f) ? o0.y : expm1f(o0.y);
      o0.z = (o0.z > 0.f) ? o0.z : expm1f(o0.z);
      o0.w = (o0.w > 0.f) ? o0.w : expm1f(o0.w);
      o1.x = (o1.x > 0.f) ? o1.x : expm1f(o1.x);
      o1.y = (o1.y > 0.f) ? o1.y : expm1f(o1.y);
      o1.z = (o1.z > 0.f) ? o1.z : expm1f(o1.z);
      o1.w = (o1.w > 0.f) ? o1.w : expm1f(o1.w);
      if constexpr (std::is_same<TOUT, __half>::value) {
        union { __half2 h[4]; uint4 u; } pk;
        pk.h[0] = __floats2half2_rn(o0.x, o0.y);
        pk.h[1] = __floats2half2_rn(o0.z, o0.w);
        pk.h[2] = __floats2half2_rn(o1.x, o1.y);
        pk.h[3] = __floats2half2_rn(o1.z, o1.w);
        *(uint4*)(OUT + (size_t)node * 128 + ch) = pk.u;
      } else {
        *(float4*)((float*)OUT + (size_t)node * 128 + ch) = o0;
        *(float4*)((float*)OUT + (size_t)node * 128 + ch + 4) = o1;
      }
    }
  } else {
    const int e = lane >> 3;        // edge-stream 0..7
    const int q = lane & 7;         // channels 4q..4q+3
    const int hsel = (q >= 4);
    const unsigned sel = hsel ? 0x03020302u : 0x01000100u;
    const float inv = hsel ? inv1 : inv0;
    __half2 hz; *(unsigned*)&hz = 0u;
    __half2 hc0 = hz, hc1 = hz;     // <=8 edges/lane in fp16 accum (dr<=64)
    for (int j = 0; j < dr; j += 8) {
      const int jj = j + e;                          // jj <= 63 always
      const int s = __shfl(srcv, jj);
      const unsigned pw = __shfl((int)pkw, jj);
      union { unsigned u; __half2 h; } wv;
      wv.u = __builtin_amdgcn_perm(pw, pw, sel);
      union { uint2 u; __half2 h[2]; } raw;
      raw.u = *(const uint2*)(H2 + (size_t)s * 32 + 4 * q);
      hc0 = __hfma2(wv.h, raw.h[0], hc0);
      hc1 = __hfma2(wv.h, raw.h[1], hc1);
    }
    float4 acc;
    float2 f;
    f = __half22float2(hc0); acc.x = f.x; acc.y = f.y;
    f = __half22float2(hc1); acc.z = f.x; acc.w = f.y;
    for (int jt = 64 + e; jt < d; jt += 8) {   // ultra-rare fallback
      const int s = col_src[begin + jt];
      const float2 a = AS[s];
      float e0 = a.x + adn.x; e0 = (e0 > 0.f) ? e0 : kNEG * e0;
      float e1 = a.y + adn.y; e1 = (e1 > 0.f) ? e1 : kNEG * e1;
      const float w = hsel ? __expf(e1) : __expf(e0);
      union { uint2 u; __half2 h[2]; } raw;
      raw.u = *(const uint2*)(H2 + (size_t)s * 32 + 4 * q);
      const float2 f0 = __half22float2(raw.h[0]);
      const float2 f1 = __half22float2(raw.h[1]);
      acc.x = fmaf(w, f0.x, acc.x); acc.y = fmaf(w, f0.y, acc.y);
      acc.z = fmaf(w, f1.x, acc.z); acc.w = fmaf(w, f1.y, acc.w);
    }
    // combine 8 edge-streams
#pragma unroll
    for (int off = 32; off >= 8; off >>= 1) {
      acc.x += __shfl_xor(acc.x, off); acc.y += __shfl_xor(acc.y, off);
      acc.z += __shfl_xor(acc.z, off); acc.w += __shfl_xor(acc.w, off);
    }
    acc.x *= inv; acc.y *= inv; acc.z *= inv; acc.w *= inv;
    // head mean: q pairs with q+4 (channel c with c+16)
    const float px = __shfl_xor(acc.x, 4);
    const float py = __shfl_xor(acc.y, 4);
    const float pz = __shfl_xor(acc.z, 4);
    const float pw = __shfl_xor(acc.w, 4);
    if (lane < 4) {
      const int ch = 4 * q;
      const float4 bv = *(const float4*)(bias + ch);
      float4 o;
      o.x = 0.5f * (acc.x + px) + bv.x;
      o.y = 0.5f * (acc.y + py) + bv.y;
      o.z = 0.5f * (acc.z + pz) + bv.z;
      o.w = 0.5f * (acc.w + pw) + bv.w;
      *(float4*)((float*)OUT + (size_t)node * 16 + ch) = o;
    }
  }
}

// ---------------- host launcher ----------------
extern "C" void kernel_launch(void* const* d_in, const int* in_sizes, int n_in,
                              void* d_out, int out_size, void* d_ws, size_t ws_size,
                              hipStream_t stream) {
  const float* x   = (const float*)d_in[0];
  const int*   ei  = (const int*)d_in[1];
  const float* W0  = (const float*)d_in[2];
  const float* as0 = (const float*)d_in[3];
  const float* ad0 = (const float*)d_in[4];
  const float* b0  = (const float*)d_in[5];
  const float* W1  = (const float*)d_in[6];
  const float* as1 = (const float*)d_in[7];
  const float* ad1 = (const float*)d_in[8];
  const float* b1  = (const float*)d_in[9];
  const float* W2  = (const float*)d_in[10];
  const float* as2 = (const float*)d_in[11];
  const float* ad2 = (const float*)d_in[12];
  const float* b2  = (const float*)d_in[13];
  float* out = (float*)d_out;

  size_t off = 0;
  auto alloc = [&](size_t bytes) -> void* {
    void* p = (char*)d_ws + off;
    off += (bytes + 255) & ~(size_t)255;
    return p;
  };
  int*    row_beg = (int*)alloc(sizeof(int) * kN);
  int*    row_cnt = (int*)alloc(sizeof(int) * kN);
  int*    bcnt    = (int*)alloc(sizeof(int) * NBUCK);
  int*    col_src = (int*)alloc(sizeof(int) * (size_t)NBUCK * CAPB);
  float2* AS      = (float2*)alloc(sizeof(float2) * kN);
  float2* AD      = (float2*)alloc(sizeof(float2) * kN);
  __half* H2      = (__half*)alloc(sizeof(__half) * (size_t)kN * 128);
  __half* actA    = (__half*)alloc(sizeof(__half) * (size_t)kN * 128);
  __half* actB    = (__half*)alloc(sizeof(__half) * (size_t)kN * 128);
  unsigned* part  = (unsigned*)actA;   // 8MB <= 12.8MB; dead before layer-0 agg writes actA
  (void)ws_size; (void)in_sizes; (void)n_in; (void)out_size;

  // ---- CSR build (single-pass bucketed partition; edge list identical for all layers) ----
  hipMemsetAsync(bcnt, 0, sizeof(int) * NBUCK, stream);
  partition_kernel<<<PGRID, 256, 0, stream>>>(ei, bcnt, part);
  finalize_kernel<<<NBUCK, 256, 0, stream>>>(part, bcnt, row_beg, row_cnt, col_src);

  // ---- layer 0 ----
  transform_kernel<128, 4, float><<<(kN + 31) / 32, 256, 0, stream>>>(x, W0, as0, ad0, H2, AS, AD, kN);
  agg_kernel<64, 0, __half><<<(kN + 3) / 4, 256, 0, stream>>>(H2, AS, AD, row_beg, row_cnt, col_src, b0, actA);

  // ---- layer 1 ----
  transform_kernel<128, 4, __half><<<(kN + 31) / 32, 256, 0, stream>>>(actA, W1, as1, ad1, H2, AS, AD, kN);
  agg_kernel<64, 0, __half><<<(kN + 3) / 4, 256, 0, stream>>>(H2, AS, AD, row_beg, row_cnt, col_src, b1, actB);

  // ---- layer 2 ----
  transform_kernel<32, 1, __half><<<(kN + 31) / 32, 256, 0, stream>>>(actB, W2, as2, ad2, H2, AS, AD, kN);
  agg_kernel<16, 1, float><<<(kN + 3) / 4, 256, 0, stream>>>(H2, AS, AD, row_beg, row_cnt, col_src, b2, out);
}